// Round 1
// baseline (3003.715 us; speedup 1.0000x reference)
//
#include <hip/hip_runtime.h>
#include <hip/hip_bf16.h>

#define EPS 1e-5f

// ---------------------------------------------------------------------------
// Fused conv3x3(SAME) + BN(eval) + ReLU + maxpool2x2.
// One thread per pooled output element; computes the 2x2 pre-pool conv
// outputs, applies affine (BN folded with conv bias), relu, max.
// Thread index order = output layout (b, co, ph, pw) -> coalesced stores.
// ---------------------------------------------------------------------------
template<int CI, int CO, int PH, int PW>
__global__ __launch_bounds__(256) void conv_bn_pool(
    const float* __restrict__ x,   // (B, CI, 2PH, 2PW)
    const float* __restrict__ w,   // (CO, CI, 3, 3)
    const float* __restrict__ cb,  // (CO)
    const float* __restrict__ g,
    const float* __restrict__ bb,
    const float* __restrict__ m,
    const float* __restrict__ v,
    float* __restrict__ out)       // (B, CO, PH, PW)
{
    const int H = 2 * PH, W = 2 * PW;
    int idx = blockIdx.x * 256 + threadIdx.x;
    int pw = idx % PW;
    int t  = idx / PW;
    int ph = t % PH;  t /= PH;
    int co = t % CO;
    int b  = t / CO;

    // fold BN + conv bias: y = conv*s + (cb*s + bb - m*s)
    float s  = g[co] * rsqrtf(v[co] + EPS);
    float sh = (cb[co] - m[co]) * s + bb[co];

    float a00 = 0.f, a01 = 0.f, a10 = 0.f, a11 = 0.f;
    const int h0 = 2 * ph, w0 = 2 * pw;
    const float* xb  = x + (b * CI) * H * W;
    const float* wco = w + co * CI * 9;

    for (int ci = 0; ci < CI; ++ci) {
        const float* xc = xb + ci * H * W;
        const float* wc = wco + ci * 9;
        float wv[9];
        #pragma unroll
        for (int i = 0; i < 9; ++i) wv[i] = wc[i];

        float p[4][4];
        #pragma unroll
        for (int dy = 0; dy < 4; ++dy) {
            int hy = h0 - 1 + dy;
            #pragma unroll
            for (int dx = 0; dx < 4; ++dx) {
                int wx = w0 - 1 + dx;
                p[dy][dx] = (hy >= 0 && hy < H && wx >= 0 && wx < W)
                              ? xc[hy * W + wx] : 0.f;
            }
        }
        #pragma unroll
        for (int ky = 0; ky < 3; ++ky)
            #pragma unroll
            for (int kx = 0; kx < 3; ++kx) {
                float wk = wv[ky * 3 + kx];
                a00 = fmaf(wk, p[ky][kx],     a00);
                a01 = fmaf(wk, p[ky][kx + 1], a01);
                a10 = fmaf(wk, p[ky + 1][kx],     a10);
                a11 = fmaf(wk, p[ky + 1][kx + 1], a11);
            }
    }
    float o = fmaxf(fmaxf(a00 * s + sh, a01 * s + sh),
                    fmaxf(a10 * s + sh, a11 * s + sh));
    out[idx] = fmaxf(o, 0.f);
}

// ---------------------------------------------------------------------------
// LRLC: basis conv (96 -> R*C = 4*128) at 16x16, per-location softmax-rank
// combine + low-rank bias + relu. Writes output TRANSPOSED: outT[k][b],
// k = c*256 + h*16 + w, so fc1 can put batch in lanes.
// Thread order: idx = ((b*128 + c)*256 + h*16 + w) -> (b,c) wave-uniform,
// so all basis-weight loads take the scalar path.
// ---------------------------------------------------------------------------
__global__ __launch_bounds__(256) void lrlc_kernel(
    const float* __restrict__ x,    // (B, 96, 16, 16)
    const float* __restrict__ bw,   // (512, 96, 3, 3), oc = r*128 + c
    const float* __restrict__ bb,   // (4, 128)
    const float* __restrict__ cwh,  // (16, 4)
    const float* __restrict__ cww,  // (16, 4)
    float* __restrict__ outT)       // (32768, 64)
{
    int idx = blockIdx.x * 256 + threadIdx.x;
    int hw = idx & 255;
    int t  = idx >> 8;
    int c  = t & 127;
    int b  = t >> 7;
    int h  = hw >> 4, w = hw & 15;

    // softmax over rank at (h, w)
    float e[4]; float mx = -1e30f;
    #pragma unroll
    for (int r = 0; r < 4; ++r) { e[r] = cwh[h * 4 + r] + cww[w * 4 + r]; mx = fmaxf(mx, e[r]); }
    float se = 0.f;
    #pragma unroll
    for (int r = 0; r < 4; ++r) { e[r] = expf(e[r] - mx); se += e[r]; }
    float inv = 1.f / se;
    #pragma unroll
    for (int r = 0; r < 4; ++r) e[r] *= inv;

    float acc[4] = {0.f, 0.f, 0.f, 0.f};
    const float* xb = x + b * 96 * 256;

    for (int ci = 0; ci < 96; ++ci) {
        const float* xc = xb + ci * 256;
        float p[3][3];
        #pragma unroll
        for (int dy = 0; dy < 3; ++dy) {
            int hy = h - 1 + dy;
            #pragma unroll
            for (int dx = 0; dx < 3; ++dx) {
                int wx = w - 1 + dx;
                p[dy][dx] = (hy >= 0 && hy < 16 && wx >= 0 && wx < 16)
                              ? xc[hy * 16 + wx] : 0.f;
            }
        }
        #pragma unroll
        for (int r = 0; r < 4; ++r) {
            const float* wr = bw + ((r * 128 + c) * 96 + ci) * 9;
            float a = 0.f;
            #pragma unroll
            for (int k = 0; k < 9; ++k) a = fmaf(wr[k], p[k / 3][k % 3], a);
            acc[r] += a;
        }
    }
    float o = 0.f;
    #pragma unroll
    for (int r = 0; r < 4; ++r) o = fmaf(e[r], acc[r] + bb[r * 128 + c], o);
    o = fmaxf(o, 0.f);
    int k = c * 256 + hw;
    outT[k * 64 + b] = o;
}

// ---------------------------------------------------------------------------
// fc1 stage: partial[ks][j][b] = sum over K-chunk of W[j,k] * XT[k][b].
// One wave per block; lane = batch. W addresses are wave-uniform -> scalar
// loads; XT loads coalesced. jtile=16, kchunk=512 (64 k-splits).
// ---------------------------------------------------------------------------
#define FC1_JT 16
#define FC1_KC 512
#define FC1_KS 64
#define FC1_NJT 32   // 512 / 16

__global__ __launch_bounds__(64) void fc1_stage(
    const float* __restrict__ xT,  // (32768, 64)
    const float* __restrict__ w,   // (512, 32768)
    float* __restrict__ partial)   // (64, 512, 64)
{
    int lane = threadIdx.x;            // = b
    int jt = blockIdx.x % FC1_NJT;
    int ks = blockIdx.x / FC1_NJT;
    int j0 = jt * FC1_JT;
    int k0 = ks * FC1_KC;

    float acc[FC1_JT];
    #pragma unroll
    for (int j = 0; j < FC1_JT; ++j) acc[j] = 0.f;

    const float* xp = xT + k0 * 64 + lane;
    const float* wp = w + j0 * 32768 + k0;

    #pragma unroll 4
    for (int k = 0; k < FC1_KC; ++k) {
        float xv = xp[k * 64];
        #pragma unroll
        for (int j = 0; j < FC1_JT; ++j)
            acc[j] = fmaf(wp[j * 32768 + k], xv, acc[j]);
    }
    #pragma unroll
    for (int j = 0; j < FC1_JT; ++j)
        partial[(ks * 512 + j0 + j) * 64 + lane] = acc[j];
}

__global__ __launch_bounds__(256) void fc1_reduce(
    const float* __restrict__ partial,  // (64, 512, 64)
    const float* __restrict__ bias,     // (512)
    float* __restrict__ out)            // (64, 512): out[b*512 + j]
{
    int idx = blockIdx.x * 256 + threadIdx.x;  // j*64 + b (read-coalesced)
    int b = idx & 63;
    int j = idx >> 6;
    float a = bias[j];
    for (int ks = 0; ks < FC1_KS; ++ks)
        a += partial[(ks * 512 + j) * 64 + b];
    out[b * 512 + j] = fmaxf(a, 0.f);
}

__global__ __launch_bounds__(256) void fc2_kernel(
    const float* __restrict__ x,    // (64, 512)
    const float* __restrict__ w,    // (10, 512)
    const float* __restrict__ bias, // (10)
    float* __restrict__ out)        // (64, 10)
{
    int idx = blockIdx.x * 256 + threadIdx.x;
    if (idx >= 640) return;
    int n = idx % 10, b = idx / 10;
    float a = bias[n];
    const float* xr = x + b * 512;
    const float* wr = w + n * 512;
    for (int j = 0; j < 512; ++j) a = fmaf(xr[j], wr[j], a);
    out[idx] = a;
}

// ---------------------------------------------------------------------------
extern "C" void kernel_launch(void* const* d_in, const int* in_sizes, int n_in,
                              void* d_out, int out_size, void* d_ws, size_t ws_size,
                              hipStream_t stream) {
    const float* x       = (const float*)d_in[0];
    const float* c1w = (const float*)d_in[1];  const float* c1b = (const float*)d_in[2];
    const float* b1g = (const float*)d_in[3];  const float* b1b = (const float*)d_in[4];
    const float* b1m = (const float*)d_in[5];  const float* b1v = (const float*)d_in[6];
    const float* c2w = (const float*)d_in[7];  const float* c2b = (const float*)d_in[8];
    const float* b2g = (const float*)d_in[9];  const float* b2b = (const float*)d_in[10];
    const float* b2m = (const float*)d_in[11]; const float* b2v = (const float*)d_in[12];
    const float* c3w = (const float*)d_in[13]; const float* c3b = (const float*)d_in[14];
    const float* b3g = (const float*)d_in[15]; const float* b3b = (const float*)d_in[16];
    const float* b3m = (const float*)d_in[17]; const float* b3v = (const float*)d_in[18];
    const float* bw  = (const float*)d_in[19]; const float* bb  = (const float*)d_in[20];
    const float* cwh = (const float*)d_in[21]; const float* cww = (const float*)d_in[22];
    const float* f1w = (const float*)d_in[23]; const float* f1b = (const float*)d_in[24];
    const float* f2w = (const float*)d_in[25]; const float* f2b = (const float*)d_in[26];
    float* out = (float*)d_out;

    float* ws = (float*)d_ws;
    // aliased layout (floats):
    float* buf1   = ws;                    // 8,388,608   (64,32,64,64)
    float* buf2   = ws + 8388608;          // 4,194,304   (64,64,32,32)
    float* buf3   = ws;                    // 1,572,864   (64,96,16,16)  [reuses buf1]
    float* outT   = ws + 1572864;          // 2,097,152   (32768,64)
    float* part   = ws + 3670016;          // 2,097,152   (64,512,64)
    float* fc1o   = ws + 5767168;          // 32,768      (64,512)

    // block 1: (64,1,128,128) -> (64,32,64,64)
    conv_bn_pool<1, 32, 64, 64><<<32768, 256, 0, stream>>>(
        x, c1w, c1b, b1g, b1b, b1m, b1v, buf1);
    // block 2: -> (64,64,32,32)
    conv_bn_pool<32, 64, 32, 32><<<16384, 256, 0, stream>>>(
        buf1, c2w, c2b, b2g, b2b, b2m, b2v, buf2);
    // block 3: -> (64,96,16,16)
    conv_bn_pool<64, 96, 16, 16><<<6144, 256, 0, stream>>>(
        buf2, c3w, c3b, b3g, b3b, b3m, b3v, buf3);
    // LRLC -> transposed activation (32768, 64)
    lrlc_kernel<<<8192, 256, 0, stream>>>(buf3, bw, bb, cwh, cww, outT);
    // fc1
    fc1_stage<<<FC1_NJT * FC1_KS, 64, 0, stream>>>(outT, f1w, part);
    fc1_reduce<<<128, 256, 0, stream>>>(part, f1b, fc1o);
    // fc2
    fc2_kernel<<<3, 256, 0, stream>>>(fc1o, f2w, f2b, out);
}

// Round 2
// 405.392 us; speedup vs baseline: 7.4094x; 7.4094x over previous
//
#include <hip/hip_runtime.h>
#include <hip/hip_bf16.h>

#define EPS 1e-5f

typedef short s16x8 __attribute__((ext_vector_type(8)));
typedef float f32x4 __attribute__((ext_vector_type(4)));

__device__ __forceinline__ unsigned short f2bf(float f) {
    unsigned u = __float_as_uint(f);
    u += 0x7fffu + ((u >> 16) & 1u);
    return (unsigned short)(u >> 16);
}

// ---------------------------------------------------------------------------
// Repack conv weights (CO,CI,3,3) f32 -> (CO, 9, CI) bf16  [k=(shift,ci) inner]
// ---------------------------------------------------------------------------
__global__ __launch_bounds__(256) void repack_w(
    const float* __restrict__ c2w, const float* __restrict__ c3w,
    const float* __restrict__ bw,
    unsigned short* __restrict__ wp2, unsigned short* __restrict__ wp3,
    unsigned short* __restrict__ wpL)
{
    int idx = blockIdx.x * 256 + threadIdx.x;
    if (idx < 18432) {                       // conv2: 64 x 9 x 32
        int co = idx / 288, rem = idx % 288, s = rem / 32, ci = rem % 32;
        wp2[idx] = f2bf(c2w[(co * 32 + ci) * 9 + s]);
    } else if (idx < 73728) {                // conv3: 96 x 9 x 64
        int i = idx - 18432;
        int co = i / 576, rem = i % 576, s = rem / 64, ci = rem % 64;
        wp3[i] = f2bf(c3w[(co * 64 + ci) * 9 + s]);
    } else if (idx < 516096) {               // lrlc: 512 x 9 x 96
        int i = idx - 73728;
        int co = i / 864, rem = i % 864, s = rem / 96, ci = rem % 96;
        wpL[i] = f2bf(bw[(co * 96 + ci) * 9 + s]);
    }
}

// ---------------------------------------------------------------------------
// conv1: CI=1 direct fp32, output NHWC bf16 (co fastest -> coalesced)
// ---------------------------------------------------------------------------
__global__ __launch_bounds__(256) void conv1_dir(
    const float* __restrict__ x,      // (64,1,128,128)
    const float* __restrict__ w,      // (32,1,3,3)
    const float* __restrict__ cbv, const float* __restrict__ gg,
    const float* __restrict__ bnb, const float* __restrict__ mm,
    const float* __restrict__ vv,
    unsigned short* __restrict__ out) // (64,64,64,32) NHWC bf16
{
    int idx = blockIdx.x * 256 + threadIdx.x;
    int co = idx & 31;
    int pw = (idx >> 5) & 63;
    int ph = (idx >> 11) & 63;
    int b  = idx >> 17;
    float scl = gg[co] * rsqrtf(vv[co] + EPS);
    float sh  = (cbv[co] - mm[co]) * scl + bnb[co];
    float wv[9];
    #pragma unroll
    for (int i = 0; i < 9; ++i) wv[i] = w[co * 9 + i];
    const float* xb = x + (size_t)b * 16384;
    int h0 = 2 * ph, w0 = 2 * pw;
    float p[4][4];
    #pragma unroll
    for (int dy = 0; dy < 4; ++dy) {
        int hy = h0 - 1 + dy;
        #pragma unroll
        for (int dx = 0; dx < 4; ++dx) {
            int wx = w0 - 1 + dx;
            p[dy][dx] = (hy >= 0 && hy < 128 && wx >= 0 && wx < 128)
                          ? xb[hy * 128 + wx] : 0.f;
        }
    }
    float a00 = 0.f, a01 = 0.f, a10 = 0.f, a11 = 0.f;
    #pragma unroll
    for (int ky = 0; ky < 3; ++ky)
        #pragma unroll
        for (int kx = 0; kx < 3; ++kx) {
            float wk = wv[ky * 3 + kx];
            a00 = fmaf(wk, p[ky][kx],         a00);
            a01 = fmaf(wk, p[ky][kx + 1],     a01);
            a10 = fmaf(wk, p[ky + 1][kx],     a10);
            a11 = fmaf(wk, p[ky + 1][kx + 1], a11);
        }
    float y0 = fmaf(a00, scl, sh), y1 = fmaf(a01, scl, sh);
    float y2 = fmaf(a10, scl, sh), y3 = fmaf(a11, scl, sh);
    float o = fmaxf(fmaxf(fmaxf(y0, y1), fmaxf(y2, y3)), 0.f);
    out[idx] = f2bf(o);
}

// ---------------------------------------------------------------------------
// Fused implicit-GEMM conv3x3 + BN + ReLU + pool2x2 via bf16 MFMA.
// Input NHWC bf16 (B, W, W, CI); weights (CO,9,CI) bf16; out NHWC bf16.
// Block: (b, h-pair). M-tile = 2 rows x W; N = CO; K = 9*CI (shift-major).
// A-tile: 4 input rows staged once (zero-padded, ci-group XOR swizzle).
// ---------------------------------------------------------------------------
template<int CI, int CO, int W, int NWM, int NWN, bool ALLB,
         int SASH, int SAMK, int SBSH, int SBMK>
__global__ __launch_bounds__(256) void conv_mfma_pool(
    const unsigned short* __restrict__ xin,
    const unsigned short* __restrict__ wpk,
    const float* __restrict__ cbv, const float* __restrict__ gg,
    const float* __restrict__ bnb, const float* __restrict__ mm,
    const float* __restrict__ vv,
    unsigned short* __restrict__ out)
{
    constexpr int WT  = W + 2;
    constexpr int NFW = CO / 16 / NWN;
    constexpr int CG  = CI / 8;
    constexpr int ASZ = 4 * WT * CI * 2;
    constexpr int BSZ = (ALLB ? 9 : 1) * CO * CI * 2;
    constexpr int KSTEPS = CI / 32;
    constexpr int PH2 = W / 2;

    __shared__ __align__(16) unsigned char sm[ASZ + BSZ];

    const int tid = threadIdx.x;
    const int wave = tid >> 6, lane = tid & 63;
    const int quad = lane >> 4, col = lane & 15;
    const int wm = wave % NWM, wn = wave / NWM;

    const int hp = blockIdx.x % PH2;
    const int b  = blockIdx.x / PH2;

    // stage A: rows h = hp*2-1 .. hp*2+2, padded w' = 0..WT-1 (w = w'-1)
    constexpr int NCHA = 4 * WT * CG;
    for (int ch = tid; ch < NCHA; ch += 256) {
        int r    = ch / (WT * CG);
        int rem  = ch % (WT * CG);
        int wp   = rem / CG;
        int slot = rem % CG;
        int g = slot ^ ((wp >> SASH) & SAMK);
        int h = hp * 2 - 1 + r;
        int w = wp - 1;
        s16x8 val = {};
        if (h >= 0 && h < W && w >= 0 && w < W)
            val = *(const s16x8*)(xin + (((size_t)(b * W + h) * W + w) * CI + g * 8));
        *(s16x8*)(sm + ch * 16) = val;
    }
    if constexpr (ALLB) {
        constexpr int NCHB = CO * 9 * CG;
        for (int ch = tid; ch < NCHB; ch += 256) {
            int co   = ch / (9 * CG);
            int rem  = ch % (9 * CG);
            int s    = rem / CG;
            int slot = rem % CG;
            int g = slot ^ ((co >> SBSH) & SBMK);
            s16x8 val = *(const s16x8*)(wpk + ((co * 9 + s) * CI + g * 8));
            *(s16x8*)(sm + ASZ + ch * 16) = val;
        }
        __syncthreads();
    }

    f32x4 acc[2][NFW];
    #pragma unroll
    for (int i = 0; i < 2; ++i)
        #pragma unroll
        for (int j = 0; j < NFW; ++j) acc[i][j] = (f32x4){0.f, 0.f, 0.f, 0.f};

    #pragma unroll
    for (int s = 0; s < 9; ++s) {
        const int dy = s / 3, dx = s % 3;
        if constexpr (!ALLB) {
            __syncthreads();
            constexpr int NCHB = CO * CG;
            for (int ch = tid; ch < NCHB; ch += 256) {
                int co = ch / CG, slot = ch % CG;
                int g = slot ^ ((co >> SBSH) & SBMK);
                s16x8 val = *(const s16x8*)(wpk + ((co * 9 + s) * CI + g * 8));
                *(s16x8*)(sm + ASZ + ch * 16) = val;
            }
            __syncthreads();
        }
        #pragma unroll
        for (int kk = 0; kk < KSTEPS; ++kk) {
            const int g = kk * 4 + quad;
            s16x8 a[2];
            #pragma unroll
            for (int mi = 0; mi < 2; ++mi) {
                int wp = wm * 16 + col + dx;    // A row = lane&15
                int r  = mi + dy;
                int addr = (r * WT + wp) * (CI * 2) + ((g ^ ((wp >> SASH) & SAMK)) << 4);
                a[mi] = *(const s16x8*)(sm + addr);
            }
            #pragma unroll
            for (int nf = 0; nf < NFW; ++nf) {
                int co_l = (wn * NFW + nf) * 16 + col;  // B col = lane&15
                int row = ALLB ? (co_l * 9 + s) : co_l;
                int addr = ASZ + row * (CI * 2) + ((g ^ ((co_l >> SBSH) & SBMK)) << 4);
                s16x8 bf = *(const s16x8*)(sm + addr);
                acc[0][nf] = __builtin_amdgcn_mfma_f32_16x16x32_bf16(a[0], bf, acc[0][nf], 0, 0, 0);
                acc[1][nf] = __builtin_amdgcn_mfma_f32_16x16x32_bf16(a[1], bf, acc[1][nf], 0, 0, 0);
            }
        }
    }

    // epilogue: BN + relu + 2x2 pool; D layout: col=lane&15, row=quad*4+reg
    #pragma unroll
    for (int nf = 0; nf < NFW; ++nf) {
        int co = (wn * NFW + nf) * 16 + col;
        float scl = gg[co] * rsqrtf(vv[co] + EPS);
        float sh  = (cbv[co] - mm[co]) * scl + bnb[co];
        #pragma unroll
        for (int pr = 0; pr < 2; ++pr) {
            float y0 = fmaf(acc[0][nf][2 * pr],     scl, sh);
            float y1 = fmaf(acc[0][nf][2 * pr + 1], scl, sh);
            float y2 = fmaf(acc[1][nf][2 * pr],     scl, sh);
            float y3 = fmaf(acc[1][nf][2 * pr + 1], scl, sh);
            float o = fmaxf(fmaxf(fmaxf(y0, y1), fmaxf(y2, y3)), 0.f);
            int pw = wm * 8 + quad * 2 + pr;
            out[((size_t)(b * PH2 + hp) * PH2 + pw) * CO + co] = f2bf(o);
        }
    }
}

// ---------------------------------------------------------------------------
// LRLC: basis conv (96 -> 4r x 128c) @16x16 + softmax-rank combine + bias
// + relu, MFMA. Block: (b, m-half, c-block of 32). BN-tile = 32c x 4r.
// Output: act[b][k] f32, k = c*256 + h*16 + w  (fc1-ready, LDS-transposed).
// ---------------------------------------------------------------------------
__global__ __launch_bounds__(256) void lrlc_mfma(
    const unsigned short* __restrict__ xin,  // (64,16,16,96) bf16
    const unsigned short* __restrict__ wpk,  // (512,9,96) bf16
    const float* __restrict__ bbias,         // (4,128)
    const float* __restrict__ cwh, const float* __restrict__ cww,
    float* __restrict__ act)                 // (64, 32768) f32
{
    constexpr int CI = 96, WT = 18, NR = 10, CG = 12;
    constexpr int ASZ = NR * WT * CI * 2;    // 34560
    constexpr int BSZ = 128 * CI * 2;        // 24576
    __shared__ __align__(16) unsigned char sm[ASZ + BSZ];
    __shared__ float cwt[256][4];
    __shared__ float ldo[128][33];

    const int tid = threadIdx.x;
    const int wave = tid >> 6, lane = tid & 63;
    const int quad = lane >> 4, col = lane & 15;

    const int cbk = blockIdx.x & 3;
    const int mb  = (blockIdx.x >> 2) & 1;
    const int b   = blockIdx.x >> 3;

    {   // softmax combining-weight table (all 256 locations)
        int h = tid >> 4, w = tid & 15;
        float e[4], mx = -1e30f;
        #pragma unroll
        for (int r = 0; r < 4; ++r) { e[r] = cwh[h * 4 + r] + cww[w * 4 + r]; mx = fmaxf(mx, e[r]); }
        float se = 0.f;
        #pragma unroll
        for (int r = 0; r < 4; ++r) { e[r] = expf(e[r] - mx); se += e[r]; }
        float inv = 1.f / se;
        #pragma unroll
        for (int r = 0; r < 4; ++r) cwt[tid][r] = e[r] * inv;
    }

    constexpr int NCHA = NR * WT * CG;  // 2160
    for (int ch = tid; ch < NCHA; ch += 256) {
        int r    = ch / (WT * CG);
        int rem  = ch % (WT * CG);
        int wp   = rem / CG, slot = rem % CG;
        int g = slot ^ ((wp >> 1) & 3);
        int h = mb * 8 + r - 1;
        int w = wp - 1;
        s16x8 val = {};
        if (h >= 0 && h < 16 && w >= 0 && w < 16)
            val = *(const s16x8*)(xin + (((size_t)(b * 16 + h) * 16 + w) * CI + g * 8));
        *(s16x8*)(sm + ch * 16) = val;
    }

    f32x4 acc[2][8];
    #pragma unroll
    for (int i = 0; i < 2; ++i)
        #pragma unroll
        for (int j = 0; j < 8; ++j) acc[i][j] = (f32x4){0.f, 0.f, 0.f, 0.f};

    #pragma unroll
    for (int s = 0; s < 9; ++s) {
        const int dy = s / 3, dx = s % 3;
        __syncthreads();
        constexpr int NCHB = 128 * CG;  // 1536
        for (int ch = tid; ch < NCHB; ch += 256) {
            int co = ch / CG, slot = ch % CG;
            int g = slot ^ ((co >> 1) & 3);
            int cog = (co >> 5) * 128 + cbk * 32 + (co & 31);
            s16x8 val = *(const s16x8*)(wpk + ((cog * 9 + s) * CI + g * 8));
            *(s16x8*)(sm + ASZ + ch * 16) = val;
        }
        __syncthreads();
        #pragma unroll
        for (int kk = 0; kk < 3; ++kk) {
            const int g = kk * 4 + quad;
            s16x8 a[2];
            #pragma unroll
            for (int mi = 0; mi < 2; ++mi) {
                int mf = wave * 2 + mi;       // Mfrag = image row
                int r  = mf + dy;
                int wp = col + dx;
                int addr = (r * WT + wp) * (CI * 2) + ((g ^ ((wp >> 1) & 3)) << 4);
                a[mi] = *(const s16x8*)(sm + addr);
            }
            #pragma unroll
            for (int nf = 0; nf < 8; ++nf) {
                int co_l = nf * 16 + col;
                int addr = ASZ + co_l * (CI * 2) + ((g ^ ((co_l >> 1) & 3)) << 4);
                s16x8 bf = *(const s16x8*)(sm + addr);
                acc[0][nf] = __builtin_amdgcn_mfma_f32_16x16x32_bf16(a[0], bf, acc[0][nf], 0, 0, 0);
                acc[1][nf] = __builtin_amdgcn_mfma_f32_16x16x32_bf16(a[1], bf, acc[1][nf], 0, 0, 0);
            }
        }
    }

    // combine over rank (nf = 2r + half), relu, stash to LDS for transpose
    #pragma unroll
    for (int mi = 0; mi < 2; ++mi) {
        int mf = wave * 2 + mi;
        #pragma unroll
        for (int half = 0; half < 2; ++half) {
            int c = cbk * 32 + half * 16 + col;
            float bb0 = bbias[c], bb1 = bbias[128 + c],
                  bb2 = bbias[256 + c], bb3 = bbias[384 + c];
            #pragma unroll
            for (int rg = 0; rg < 4; ++rg) {
                int hwl = mf * 16 + quad * 4 + rg;
                int hwg = mb * 128 + hwl;
                float o = cwt[hwg][0] * (acc[mi][half + 0][rg] + bb0)
                        + cwt[hwg][1] * (acc[mi][half + 2][rg] + bb1)
                        + cwt[hwg][2] * (acc[mi][half + 4][rg] + bb2)
                        + cwt[hwg][3] * (acc[mi][half + 6][rg] + bb3);
                ldo[hwl][half * 16 + col] = fmaxf(o, 0.f);
            }
        }
    }
    __syncthreads();
    {   // coalesced write-out: act[b][ (cbk*32+cl)*256 + mb*128 + hw ]
        int cl = tid >> 3;   // 0..31
        int sg = tid & 7;    // 0..7
        size_t base = (size_t)b * 32768 + (cbk * 32 + cl) * 256 + mb * 128 + sg * 16;
        #pragma unroll
        for (int i = 0; i < 16; i += 4) {
            float4 v;
            v.x = ldo[sg * 16 + i + 0][cl];
            v.y = ldo[sg * 16 + i + 1][cl];
            v.z = ldo[sg * 16 + i + 2][cl];
            v.w = ldo[sg * 16 + i + 3][cl];
            *(float4*)(act + base + i) = v;
        }
    }
}

// ---------------------------------------------------------------------------
// fc1: out[b][j] = relu(sum_k W[j][k] * act[b][k] + bias). LDS-transposed
// chunks: coalesced act reads, lane=b compute, scalar W reads.
// grid = 16 jt x 32 ks; block j-tile = 32 (wave*8), K-chunk = 1024.
// ---------------------------------------------------------------------------
__global__ __launch_bounds__(256) void fc1_stage2(
    const float* __restrict__ act,   // (64, 32768)
    const float* __restrict__ w,     // (512, 32768)
    float* __restrict__ partial)     // (32, 512, 64)
{
    __shared__ float lx[128 * 65];
    const int tid = threadIdx.x;
    const int wave = tid >> 6, lane = tid & 63;
    const int jt = blockIdx.x & 15;
    const int ks = blockIdx.x >> 4;
    const int k0 = ks * 1024;
    const int jbase = __builtin_amdgcn_readfirstlane(jt * 32 + wave * 8);

    float acc[8];
    #pragma unroll
    for (int jj = 0; jj < 8; ++jj) acc[jj] = 0.f;

    const int bb_ = tid >> 2, qd = tid & 3;

    for (int sc = 0; sc < 8; ++sc) {
        __syncthreads();
        const float* src = act + (size_t)bb_ * 32768 + k0 + sc * 128 + qd * 32;
        #pragma unroll
        for (int u = 0; u < 8; ++u) {
            float4 v = *(const float4*)(src + u * 4);
            int kk = qd * 32 + u * 4;
            lx[(kk + 0) * 65 + bb_] = v.x;
            lx[(kk + 1) * 65 + bb_] = v.y;
            lx[(kk + 2) * 65 + bb_] = v.z;
            lx[(kk + 3) * 65 + bb_] = v.w;
        }
        __syncthreads();
        const float* wr = w + (size_t)jbase * 32768 + k0 + sc * 128;
        #pragma unroll 4
        for (int k = 0; k < 128; ++k) {
            float xv = lx[k * 65 + lane];
            #pragma unroll
            for (int jj = 0; jj < 8; ++jj)
                acc[jj] = fmaf(wr[(size_t)jj * 32768 + k], xv, acc[jj]);
        }
    }
    #pragma unroll
    for (int jj = 0; jj < 8; ++jj)
        partial[((size_t)ks * 512 + jbase + jj) * 64 + lane] = acc[jj];
}

__global__ __launch_bounds__(256) void fc1_reduce2(
    const float* __restrict__ partial, const float* __restrict__ bias,
    float* __restrict__ out)             // (64,512)
{
    int idx = blockIdx.x * 256 + threadIdx.x;  // j*64 + b
    int b = idx & 63, j = idx >> 6;
    float a = bias[j];
    for (int ks = 0; ks < 32; ++ks)
        a += partial[((size_t)ks * 512 + j) * 64 + b];
    out[b * 512 + j] = fmaxf(a, 0.f);
}

__global__ __launch_bounds__(256) void fc2_kernel(
    const float* __restrict__ x,    // (64, 512)
    const float* __restrict__ w,    // (10, 512)
    const float* __restrict__ bias,
    float* __restrict__ out)        // (64, 10)
{
    int idx = blockIdx.x * 256 + threadIdx.x;
    if (idx >= 640) return;
    int n = idx % 10, b = idx / 10;
    float a = bias[n];
    const float* xr = x + b * 512;
    const float* wr = w + n * 512;
    for (int j = 0; j < 512; ++j) a = fmaf(xr[j], wr[j], a);
    out[idx] = a;
}

// ---------------------------------------------------------------------------
extern "C" void kernel_launch(void* const* d_in, const int* in_sizes, int n_in,
                              void* d_out, int out_size, void* d_ws, size_t ws_size,
                              hipStream_t stream) {
    const float* x   = (const float*)d_in[0];
    const float* c1w = (const float*)d_in[1];  const float* c1b = (const float*)d_in[2];
    const float* b1g = (const float*)d_in[3];  const float* b1b = (const float*)d_in[4];
    const float* b1m = (const float*)d_in[5];  const float* b1v = (const float*)d_in[6];
    const float* c2w = (const float*)d_in[7];  const float* c2b = (const float*)d_in[8];
    const float* b2g = (const float*)d_in[9];  const float* b2b = (const float*)d_in[10];
    const float* b2m = (const float*)d_in[11]; const float* b2v = (const float*)d_in[12];
    const float* c3w = (const float*)d_in[13]; const float* c3b = (const float*)d_in[14];
    const float* b3g = (const float*)d_in[15]; const float* b3b = (const float*)d_in[16];
    const float* b3m = (const float*)d_in[17]; const float* b3v = (const float*)d_in[18];
    const float* bw  = (const float*)d_in[19]; const float* bb  = (const float*)d_in[20];
    const float* cwh = (const float*)d_in[21]; const float* cww = (const float*)d_in[22];
    const float* f1w = (const float*)d_in[23]; const float* f1b = (const float*)d_in[24];
    const float* f2w = (const float*)d_in[25]; const float* f2b = (const float*)d_in[26];
    float* out = (float*)d_out;

    char* ws = (char*)d_ws;
    // region [0, 16.7MB): act1 (conv1 out); after conv2 it is reused for
    // act3 / actF / partial / fc1o (all consumers strictly ordered).
    unsigned short* act1 = (unsigned short*)(ws + 0);           // 16,777,216 B
    unsigned short* act3 = (unsigned short*)(ws + 0);           //  3,145,728 B
    float*          actF = (float*)(ws + 4194304);              //  8,388,608 B
    float*          fc1o = (float*)(ws + 4194304);              // reuses actF after fc1_stage
    float*          part = (float*)(ws + 12582912);             //  4,194,304 B
    unsigned short* act2 = (unsigned short*)(ws + 16777216);    //  8,388,608 B
    unsigned short* wp2  = (unsigned short*)(ws + 25165824);    //     36,864 B
    unsigned short* wp3  = (unsigned short*)(ws + 25202688);    //    110,592 B
    unsigned short* wpL  = (unsigned short*)(ws + 25313280);    //    884,736 B

    repack_w<<<2016, 256, 0, stream>>>(c2w, c3w, bw, wp2, wp3, wpL);

    conv1_dir<<<32768, 256, 0, stream>>>(x, c1w, c1b, b1g, b1b, b1m, b1v, act1);

    // conv2: CI=32 CO=64 W=64; 4 M-waves; all-shift B staging; swz shifts 1/1
    conv_mfma_pool<32, 64, 64, 4, 1, true, 1, 3, 1, 3>
        <<<2048, 256, 0, stream>>>(act1, wp2, c2b, b2g, b2b, b2m, b2v, act2);

    // conv3: CI=64 CO=96 W=32; 2x2 waves; per-shift B staging; swz shifts 0/0
    conv_mfma_pool<64, 96, 32, 2, 2, false, 0, 7, 0, 7>
        <<<1024, 256, 0, stream>>>(act2, wp3, c3b, b3g, b3b, b3m, b3v, act3);

    lrlc_mfma<<<512, 256, 0, stream>>>(act3, wpL, bb, cwh, cww, actF);

    fc1_stage2<<<512, 256, 0, stream>>>(actF, f1w, part);
    fc1_reduce2<<<128, 256, 0, stream>>>(part, f1b, fc1o);
    fc2_kernel<<<3, 256, 0, stream>>>(fc1o, f2w, f2b, out);
}

// Round 5
// 172.828 us; speedup vs baseline: 17.3798x; 2.3456x over previous
//
#include <hip/hip_runtime.h>
#include <hip/hip_bf16.h>

#define EPS 1e-5f

typedef short s16x8 __attribute__((ext_vector_type(8)));
typedef float f32x4 __attribute__((ext_vector_type(4)));

__device__ __forceinline__ unsigned short f2bf(float f) {
    unsigned u = __float_as_uint(f);
    u += 0x7fffu + ((u >> 16) & 1u);
    return (unsigned short)(u >> 16);
}

// ---------------------------------------------------------------------------
// Repack conv weights (CO,CI,3,3) f32 -> (CO, 9, CI) bf16  [k=(shift,ci) inner]
// ---------------------------------------------------------------------------
__global__ __launch_bounds__(256) void repack_w(
    const float* __restrict__ c2w, const float* __restrict__ c3w,
    const float* __restrict__ bw,
    unsigned short* __restrict__ wp2, unsigned short* __restrict__ wp3,
    unsigned short* __restrict__ wpL)
{
    int idx = blockIdx.x * 256 + threadIdx.x;
    if (idx < 18432) {                       // conv2: 64 x 9 x 32
        int co = idx / 288, rem = idx % 288, s = rem / 32, ci = rem % 32;
        wp2[idx] = f2bf(c2w[(co * 32 + ci) * 9 + s]);
    } else if (idx < 73728) {                // conv3: 96 x 9 x 64
        int i = idx - 18432;
        int co = i / 576, rem = i % 576, s = rem / 64, ci = rem % 64;
        wp3[i] = f2bf(c3w[(co * 64 + ci) * 9 + s]);
    } else if (idx < 516096) {               // lrlc: 512 x 9 x 96
        int i = idx - 73728;
        int co = i / 864, rem = i % 864, s = rem / 96, ci = rem % 96;
        wpL[i] = f2bf(bw[(co * 96 + ci) * 9 + s]);
    }
}

// ---------------------------------------------------------------------------
// conv1: CI=1 direct fp32, output NHWC bf16 (co fastest -> coalesced)
// ---------------------------------------------------------------------------
__global__ __launch_bounds__(256) void conv1_dir(
    const float* __restrict__ x,      // (64,1,128,128)
    const float* __restrict__ w,      // (32,1,3,3)
    const float* __restrict__ cbv, const float* __restrict__ gg,
    const float* __restrict__ bnb, const float* __restrict__ mm,
    const float* __restrict__ vv,
    unsigned short* __restrict__ out) // (64,64,64,32) NHWC bf16
{
    int idx = blockIdx.x * 256 + threadIdx.x;
    int co = idx & 31;
    int pw = (idx >> 5) & 63;
    int ph = (idx >> 11) & 63;
    int b  = idx >> 17;
    float scl = gg[co] * rsqrtf(vv[co] + EPS);
    float sh  = (cbv[co] - mm[co]) * scl + bnb[co];
    float wv[9];
    #pragma unroll
    for (int i = 0; i < 9; ++i) wv[i] = w[co * 9 + i];
    const float* xb = x + (size_t)b * 16384;
    int h0 = 2 * ph, w0 = 2 * pw;
    float p[4][4];
    #pragma unroll
    for (int dy = 0; dy < 4; ++dy) {
        int hy = h0 - 1 + dy;
        #pragma unroll
        for (int dx = 0; dx < 4; ++dx) {
            int wx = w0 - 1 + dx;
            p[dy][dx] = (hy >= 0 && hy < 128 && wx >= 0 && wx < 128)
                          ? xb[hy * 128 + wx] : 0.f;
        }
    }
    float a00 = 0.f, a01 = 0.f, a10 = 0.f, a11 = 0.f;
    #pragma unroll
    for (int ky = 0; ky < 3; ++ky)
        #pragma unroll
        for (int kx = 0; kx < 3; ++kx) {
            float wk = wv[ky * 3 + kx];
            a00 = fmaf(wk, p[ky][kx],         a00);
            a01 = fmaf(wk, p[ky][kx + 1],     a01);
            a10 = fmaf(wk, p[ky + 1][kx],     a10);
            a11 = fmaf(wk, p[ky + 1][kx + 1], a11);
        }
    float y0 = fmaf(a00, scl, sh), y1 = fmaf(a01, scl, sh);
    float y2 = fmaf(a10, scl, sh), y3 = fmaf(a11, scl, sh);
    float o = fmaxf(fmaxf(fmaxf(y0, y1), fmaxf(y2, y3)), 0.f);
    out[idx] = f2bf(o);
}

// ---------------------------------------------------------------------------
// Fused implicit-GEMM conv3x3 + BN + ReLU + pool2x2 via bf16 MFMA.
// ---------------------------------------------------------------------------
template<int CI, int CO, int W, int NWM, int NWN, bool ALLB,
         int SASH, int SAMK, int SBSH, int SBMK>
__global__ __launch_bounds__(256) void conv_mfma_pool(
    const unsigned short* __restrict__ xin,
    const unsigned short* __restrict__ wpk,
    const float* __restrict__ cbv, const float* __restrict__ gg,
    const float* __restrict__ bnb, const float* __restrict__ mm,
    const float* __restrict__ vv,
    unsigned short* __restrict__ out)
{
    constexpr int WT  = W + 2;
    constexpr int NFW = CO / 16 / NWN;
    constexpr int CG  = CI / 8;
    constexpr int ASZ = 4 * WT * CI * 2;
    constexpr int BSZ = (ALLB ? 9 : 1) * CO * CI * 2;
    constexpr int KSTEPS = CI / 32;
    constexpr int PH2 = W / 2;

    __shared__ __align__(16) unsigned char sm[ASZ + BSZ];

    const int tid = threadIdx.x;
    const int wave = tid >> 6, lane = tid & 63;
    const int quad = lane >> 4, col = lane & 15;
    const int wm = wave % NWM, wn = wave / NWM;

    const int hp = blockIdx.x % PH2;
    const int b  = blockIdx.x / PH2;

    constexpr int NCHA = 4 * WT * CG;
    for (int ch = tid; ch < NCHA; ch += 256) {
        int r    = ch / (WT * CG);
        int rem  = ch % (WT * CG);
        int wp   = rem / CG;
        int slot = rem % CG;
        int g = slot ^ ((wp >> SASH) & SAMK);
        int h = hp * 2 - 1 + r;
        int w = wp - 1;
        s16x8 val = {};
        if (h >= 0 && h < W && w >= 0 && w < W)
            val = *(const s16x8*)(xin + (((size_t)(b * W + h) * W + w) * CI + g * 8));
        *(s16x8*)(sm + ch * 16) = val;
    }
    if constexpr (ALLB) {
        constexpr int NCHB = CO * 9 * CG;
        for (int ch = tid; ch < NCHB; ch += 256) {
            int co   = ch / (9 * CG);
            int rem  = ch % (9 * CG);
            int s    = rem / CG;
            int slot = rem % CG;
            int g = slot ^ ((co >> SBSH) & SBMK);
            s16x8 val = *(const s16x8*)(wpk + ((co * 9 + s) * CI + g * 8));
            *(s16x8*)(sm + ASZ + ch * 16) = val;
        }
        __syncthreads();
    }

    f32x4 acc[2][NFW];
    #pragma unroll
    for (int i = 0; i < 2; ++i)
        #pragma unroll
        for (int j = 0; j < NFW; ++j) acc[i][j] = (f32x4){0.f, 0.f, 0.f, 0.f};

    #pragma unroll
    for (int s = 0; s < 9; ++s) {
        const int dy = s / 3, dx = s % 3;
        if constexpr (!ALLB) {
            __syncthreads();
            constexpr int NCHB = CO * CG;
            for (int ch = tid; ch < NCHB; ch += 256) {
                int co = ch / CG, slot = ch % CG;
                int g = slot ^ ((co >> SBSH) & SBMK);
                s16x8 val = *(const s16x8*)(wpk + ((co * 9 + s) * CI + g * 8));
                *(s16x8*)(sm + ASZ + ch * 16) = val;
            }
            __syncthreads();
        }
        #pragma unroll
        for (int kk = 0; kk < KSTEPS; ++kk) {
            const int g = kk * 4 + quad;
            s16x8 a[2];
            #pragma unroll
            for (int mi = 0; mi < 2; ++mi) {
                int wp = wm * 16 + col + dx;
                int r  = mi + dy;
                int addr = (r * WT + wp) * (CI * 2) + ((g ^ ((wp >> SASH) & SAMK)) << 4);
                a[mi] = *(const s16x8*)(sm + addr);
            }
            #pragma unroll
            for (int nf = 0; nf < NFW; ++nf) {
                int co_l = (wn * NFW + nf) * 16 + col;
                int row = ALLB ? (co_l * 9 + s) : co_l;
                int addr = ASZ + row * (CI * 2) + ((g ^ ((co_l >> SBSH) & SBMK)) << 4);
                s16x8 bf = *(const s16x8*)(sm + addr);
                acc[0][nf] = __builtin_amdgcn_mfma_f32_16x16x32_bf16(a[0], bf, acc[0][nf], 0, 0, 0);
                acc[1][nf] = __builtin_amdgcn_mfma_f32_16x16x32_bf16(a[1], bf, acc[1][nf], 0, 0, 0);
            }
        }
    }

    #pragma unroll
    for (int nf = 0; nf < NFW; ++nf) {
        int co = (wn * NFW + nf) * 16 + col;
        float scl = gg[co] * rsqrtf(vv[co] + EPS);
        float sh  = (cbv[co] - mm[co]) * scl + bnb[co];
        #pragma unroll
        for (int pr = 0; pr < 2; ++pr) {
            float y0 = fmaf(acc[0][nf][2 * pr],     scl, sh);
            float y1 = fmaf(acc[0][nf][2 * pr + 1], scl, sh);
            float y2 = fmaf(acc[1][nf][2 * pr],     scl, sh);
            float y3 = fmaf(acc[1][nf][2 * pr + 1], scl, sh);
            float o = fmaxf(fmaxf(fmaxf(y0, y1), fmaxf(y2, y3)), 0.f);
            int pw = wm * 8 + quad * 2 + pr;
            out[((size_t)(b * PH2 + hp) * PH2 + pw) * CO + co] = f2bf(o);
        }
    }
}

// ---------------------------------------------------------------------------
// LRLC: basis conv + softmax-rank combine + bias + relu, MFMA (R2-exact).
// Output: act[b][k] f32, k = c*256 + h*16 + w.
// ---------------------------------------------------------------------------
__global__ __launch_bounds__(256) void lrlc_mfma(
    const unsigned short* __restrict__ xin,  // (64,16,16,96) bf16
    const unsigned short* __restrict__ wpk,  // (512,9,96) bf16
    const float* __restrict__ bbias,         // (4,128)
    const float* __restrict__ cwh, const float* __restrict__ cww,
    float* __restrict__ act)                 // (64, 32768) f32
{
    constexpr int CI = 96, WT = 18, NR = 10, CG = 12;
    constexpr int ASZ = NR * WT * CI * 2;    // 34560
    constexpr int BSZ = 128 * CI * 2;        // 24576
    __shared__ __align__(16) unsigned char sm[ASZ + BSZ];
    __shared__ float cwt[256][4];
    __shared__ float ldo[128][33];

    const int tid = threadIdx.x;
    const int wave = tid >> 6, lane = tid & 63;
    const int quad = lane >> 4, col = lane & 15;

    const int cbk = blockIdx.x & 3;
    const int mb  = (blockIdx.x >> 2) & 1;
    const int b   = blockIdx.x >> 3;

    {
        int h = tid >> 4, w = tid & 15;
        float e[4], mx = -1e30f;
        #pragma unroll
        for (int r = 0; r < 4; ++r) { e[r] = cwh[h * 4 + r] + cww[w * 4 + r]; mx = fmaxf(mx, e[r]); }
        float se = 0.f;
        #pragma unroll
        for (int r = 0; r < 4; ++r) { e[r] = expf(e[r] - mx); se += e[r]; }
        float inv = 1.f / se;
        #pragma unroll
        for (int r = 0; r < 4; ++r) cwt[tid][r] = e[r] * inv;
    }

    constexpr int NCHA = NR * WT * CG;
    for (int ch = tid; ch < NCHA; ch += 256) {
        int r    = ch / (WT * CG);
        int rem  = ch % (WT * CG);
        int wp   = rem / CG, slot = rem % CG;
        int g = slot ^ ((wp >> 1) & 3);
        int h = mb * 8 + r - 1;
        int w = wp - 1;
        s16x8 val = {};
        if (h >= 0 && h < 16 && w >= 0 && w < 16)
            val = *(const s16x8*)(xin + (((size_t)(b * 16 + h) * 16 + w) * CI + g * 8));
        *(s16x8*)(sm + ch * 16) = val;
    }

    f32x4 acc[2][8];
    #pragma unroll
    for (int i = 0; i < 2; ++i)
        #pragma unroll
        for (int j = 0; j < 8; ++j) acc[i][j] = (f32x4){0.f, 0.f, 0.f, 0.f};

    #pragma unroll
    for (int s = 0; s < 9; ++s) {
        const int dy = s / 3, dx = s % 3;
        __syncthreads();
        constexpr int NCHB = 128 * CG;
        for (int ch = tid; ch < NCHB; ch += 256) {
            int co = ch / CG, slot = ch % CG;
            int g = slot ^ ((co >> 1) & 3);
            int cog = (co >> 5) * 128 + cbk * 32 + (co & 31);
            s16x8 val = *(const s16x8*)(wpk + ((cog * 9 + s) * CI + g * 8));
            *(s16x8*)(sm + ASZ + ch * 16) = val;
        }
        __syncthreads();
        #pragma unroll
        for (int kk = 0; kk < 3; ++kk) {
            const int g = kk * 4 + quad;
            s16x8 a[2];
            #pragma unroll
            for (int mi = 0; mi < 2; ++mi) {
                int mf = wave * 2 + mi;
                int r  = mf + dy;
                int wp = col + dx;
                int addr = (r * WT + wp) * (CI * 2) + ((g ^ ((wp >> 1) & 3)) << 4);
                a[mi] = *(const s16x8*)(sm + addr);
            }
            #pragma unroll
            for (int nf = 0; nf < 8; ++nf) {
                int co_l = nf * 16 + col;
                int addr = ASZ + co_l * (CI * 2) + ((g ^ ((co_l >> 1) & 3)) << 4);
                s16x8 bf = *(const s16x8*)(sm + addr);
                acc[0][nf] = __builtin_amdgcn_mfma_f32_16x16x32_bf16(a[0], bf, acc[0][nf], 0, 0, 0);
                acc[1][nf] = __builtin_amdgcn_mfma_f32_16x16x32_bf16(a[1], bf, acc[1][nf], 0, 0, 0);
            }
        }
    }

    #pragma unroll
    for (int mi = 0; mi < 2; ++mi) {
        int mf = wave * 2 + mi;
        #pragma unroll
        for (int half = 0; half < 2; ++half) {
            int c = cbk * 32 + half * 16 + col;
            float bb0 = bbias[c], bb1 = bbias[128 + c],
                  bb2 = bbias[256 + c], bb3 = bbias[384 + c];
            #pragma unroll
            for (int rg = 0; rg < 4; ++rg) {
                int hwl = mf * 16 + quad * 4 + rg;
                int hwg = mb * 128 + hwl;
                float o = cwt[hwg][0] * (acc[mi][half + 0][rg] + bb0)
                        + cwt[hwg][1] * (acc[mi][half + 2][rg] + bb1)
                        + cwt[hwg][2] * (acc[mi][half + 4][rg] + bb2)
                        + cwt[hwg][3] * (acc[mi][half + 6][rg] + bb3);
                ldo[hwl][half * 16 + col] = fmaxf(o, 0.f);
            }
        }
    }
    __syncthreads();
    {
        int cl = tid >> 3;   // 0..31
        int sg = tid & 7;    // 0..7
        size_t base = (size_t)b * 32768 + (cbk * 32 + cl) * 256 + mb * 128 + sg * 16;
        #pragma unroll
        for (int i = 0; i < 16; i += 4) {
            float4 v;
            v.x = ldo[sg * 16 + i + 0][cl];
            v.y = ldo[sg * 16 + i + 1][cl];
            v.z = ldo[sg * 16 + i + 2][cl];
            v.w = ldo[sg * 16 + i + 3][cl];
            *(float4*)(act + base + i) = v;
        }
    }
}

// ---------------------------------------------------------------------------
// scalar f32 -> bf16 conversion of the fc1 activation (proven store pattern)
// ---------------------------------------------------------------------------
__global__ __launch_bounds__(256) void cvt_act(
    const float* __restrict__ a, unsigned short* __restrict__ o)
{
    int i = blockIdx.x * 256 + threadIdx.x;   // 2,097,152 total
    o[i] = f2bf(a[i]);
}

// ---------------------------------------------------------------------------
// fc1 MFMA GEMM, conv-exact operand path: BOTH operands staged to LDS and
// fragment-read as s16x8 (W converted f32->bf16 then ds_write, like conv's
// register-constructed zero-fill staging). 64j x 64b tile, K-chunk 1024
// (4 x 256 sub-chunks), 32 K-splits, per-wave-owned 32j x 32b outputs.
// ---------------------------------------------------------------------------
__global__ __launch_bounds__(256) void fc1_lds(
    const unsigned short* __restrict__ actB, // (64, 32768) bf16
    const float* __restrict__ w,             // (512, 32768) f32
    float* __restrict__ partial)             // (32, 512, 64)
{
    __shared__ __align__(16) unsigned short Wl[64 * 256];
    __shared__ __align__(16) unsigned short Al[64 * 256];

    const int tid = threadIdx.x;
    const int wave = tid >> 6, lane = tid & 63;
    const int quad = lane >> 4, col = lane & 15;
    const int wm = wave & 1, wn = wave >> 1;
    const int jt = blockIdx.x & 7;
    const int ks = blockIdx.x >> 3;

    const int rt  = tid >> 2;     // staging row 0..63
    const int seg = tid & 3;      // 64-k segment 0..3

    f32x4 acc[2][2];
    #pragma unroll
    for (int i = 0; i < 2; ++i)
        #pragma unroll
        for (int j = 0; j < 2; ++j) acc[i][j] = (f32x4){0.f, 0.f, 0.f, 0.f};

    for (int c = 0; c < 4; ++c) {
        const int k0 = ks * 1024 + c * 256;
        __syncthreads();
        // stage W rows jt*64+rt (f32 -> bf16 -> LDS, XOR group swizzle rt&7)
        const float* wsrc = w + (size_t)(jt * 64 + rt) * 32768 + k0 + seg * 64;
        #pragma unroll
        for (int u = 0; u < 8; ++u) {
            float4 f0 = *(const float4*)(wsrc + u * 8);
            float4 f1 = *(const float4*)(wsrc + u * 8 + 4);
            s16x8 v;
            v[0] = (short)f2bf(f0.x); v[1] = (short)f2bf(f0.y);
            v[2] = (short)f2bf(f0.z); v[3] = (short)f2bf(f0.w);
            v[4] = (short)f2bf(f1.x); v[5] = (short)f2bf(f1.y);
            v[6] = (short)f2bf(f1.z); v[7] = (short)f2bf(f1.w);
            int phys = (seg * 8 + u) ^ (rt & 7);
            *(s16x8*)(Wl + rt * 256 + phys * 8) = v;
        }
        // stage act rows rt (b), same swizzle
        const unsigned short* asrc = actB + (size_t)rt * 32768 + k0 + seg * 64;
        #pragma unroll
        for (int u = 0; u < 8; ++u) {
            s16x8 v = *(const s16x8*)(asrc + u * 8);
            int phys = (seg * 8 + u) ^ (rt & 7);
            *(s16x8*)(Al + rt * 256 + phys * 8) = v;
        }
        __syncthreads();
        #pragma unroll
        for (int kk = 0; kk < 8; ++kk) {
            const int gg = kk * 4 + quad;
            s16x8 a[2], bb[2];
            #pragma unroll
            for (int mf = 0; mf < 2; ++mf) {
                int j_l = wm * 32 + mf * 16 + col;
                a[mf] = *(const s16x8*)(Wl + j_l * 256 + ((gg ^ (j_l & 7)) << 3));
            }
            #pragma unroll
            for (int bg = 0; bg < 2; ++bg) {
                int b_l = wn * 32 + bg * 16 + col;
                bb[bg] = *(const s16x8*)(Al + b_l * 256 + ((gg ^ (b_l & 7)) << 3));
            }
            #pragma unroll
            for (int mf = 0; mf < 2; ++mf)
                #pragma unroll
                for (int bg = 0; bg < 2; ++bg)
                    acc[mf][bg] = __builtin_amdgcn_mfma_f32_16x16x32_bf16(
                        a[mf], bb[bg], acc[mf][bg], 0, 0, 0);
        }
    }
    // D layout: row(j_local) = quad*4+reg, col(b_local) = lane&15
    #pragma unroll
    for (int mf = 0; mf < 2; ++mf)
        #pragma unroll
        for (int bg = 0; bg < 2; ++bg)
            #pragma unroll
            for (int r = 0; r < 4; ++r) {
                int j = jt * 64 + wm * 32 + mf * 16 + quad * 4 + r;
                int b = wn * 32 + bg * 16 + col;
                partial[((size_t)ks * 512 + j) * 64 + b] = acc[mf][bg][r];
            }
}

__global__ __launch_bounds__(256) void fc1_reduce4(
    const float* __restrict__ partial, const float* __restrict__ bias,
    float* __restrict__ out)             // (64,512)
{
    int idx = blockIdx.x * 256 + threadIdx.x;  // j*64 + b
    int b = idx & 63, j = idx >> 6;
    float a = bias[j];
    #pragma unroll 4
    for (int ks = 0; ks < 32; ++ks)
        a += partial[((size_t)ks * 512 + j) * 64 + b];
    out[b * 512 + j] = fmaxf(a, 0.f);
}

__global__ __launch_bounds__(256) void fc2_kernel(
    const float* __restrict__ x,    // (64, 512)
    const float* __restrict__ w,    // (10, 512)
    const float* __restrict__ bias,
    float* __restrict__ out)        // (64, 10)
{
    int idx = blockIdx.x * 256 + threadIdx.x;
    if (idx >= 640) return;
    int n = idx % 10, b = idx / 10;
    float a = bias[n];
    const float* xr = x + b * 512;
    const float* wr = w + n * 512;
    for (int j = 0; j < 512; ++j) a = fmaf(xr[j], wr[j], a);
    out[idx] = a;
}

// ---------------------------------------------------------------------------
extern "C" void kernel_launch(void* const* d_in, const int* in_sizes, int n_in,
                              void* d_out, int out_size, void* d_ws, size_t ws_size,
                              hipStream_t stream) {
    const float* x   = (const float*)d_in[0];
    const float* c1w = (const float*)d_in[1];  const float* c1b = (const float*)d_in[2];
    const float* b1g = (const float*)d_in[3];  const float* b1b = (const float*)d_in[4];
    const float* b1m = (const float*)d_in[5];  const float* b1v = (const float*)d_in[6];
    const float* c2w = (const float*)d_in[7];  const float* c2b = (const float*)d_in[8];
    const float* b2g = (const float*)d_in[9];  const float* b2b = (const float*)d_in[10];
    const float* b2m = (const float*)d_in[11]; const float* b2v = (const float*)d_in[12];
    const float* c3w = (const float*)d_in[13]; const float* c3b = (const float*)d_in[14];
    const float* b3g = (const float*)d_in[15]; const float* b3b = (const float*)d_in[16];
    const float* b3m = (const float*)d_in[17]; const float* b3v = (const float*)d_in[18];
    const float* bw  = (const float*)d_in[19]; const float* bb  = (const float*)d_in[20];
    const float* cwh = (const float*)d_in[21]; const float* cww = (const float*)d_in[22];
    const float* f1w = (const float*)d_in[23]; const float* f1b = (const float*)d_in[24];
    const float* f2w = (const float*)d_in[25]; const float* f2b = (const float*)d_in[26];
    float* out = (float*)d_out;

    char* ws = (char*)d_ws;
    unsigned short* act1 = (unsigned short*)(ws + 0);           // 16,777,216 B
    unsigned short* act3 = (unsigned short*)(ws + 0);           //  3,145,728 B (after act1 dead)
    unsigned short* actB = (unsigned short*)(ws + 0);           //  4,194,304 B (after act3 dead)
    float*          actF = (float*)(ws + 4194304);              //  8,388,608 B (64x32768 f32)
    float*          part = (float*)(ws + 12582912);             //  4,194,304 B (32x512x64)
    float*          fc1o = (float*)(ws + 16777216);             //    131,072 B (act2 region, dead)
    unsigned short* act2 = (unsigned short*)(ws + 16777216);    //  8,388,608 B
    unsigned short* wp2  = (unsigned short*)(ws + 25165824);    //     36,864 B
    unsigned short* wp3  = (unsigned short*)(ws + 25202688);    //    110,592 B
    unsigned short* wpL  = (unsigned short*)(ws + 25313280);    //    884,736 B

    repack_w<<<2016, 256, 0, stream>>>(c2w, c3w, bw, wp2, wp3, wpL);

    conv1_dir<<<32768, 256, 0, stream>>>(x, c1w, c1b, b1g, b1b, b1m, b1v, act1);

    conv_mfma_pool<32, 64, 64, 4, 1, true, 1, 3, 1, 3>
        <<<2048, 256, 0, stream>>>(act1, wp2, c2b, b2g, b2b, b2m, b2v, act2);

    conv_mfma_pool<64, 96, 32, 2, 2, false, 0, 7, 0, 7>
        <<<1024, 256, 0, stream>>>(act2, wp3, c3b, b3g, b3b, b3m, b3v, act3);

    lrlc_mfma<<<512, 256, 0, stream>>>(act3, wpL, bb, cwh, cww, actF);

    cvt_act<<<8192, 256, 0, stream>>>(actF, actB);

    fc1_lds<<<256, 256, 0, stream>>>(actB, f1w, part);
    fc1_reduce4<<<128, 256, 0, stream>>>(part, f1b, fc1o);
    fc2_kernel<<<3, 256, 0, stream>>>(fc1o, f2w, f2b, out);
}

// Round 6
// 154.059 us; speedup vs baseline: 19.4972x; 1.1218x over previous
//
#include <hip/hip_runtime.h>
#include <hip/hip_bf16.h>

#define EPS 1e-5f

typedef short s16x8 __attribute__((ext_vector_type(8)));
typedef float f32x4 __attribute__((ext_vector_type(4)));

__device__ __forceinline__ unsigned short f2bf(float f) {
    unsigned u = __float_as_uint(f);
    u += 0x7fffu + ((u >> 16) & 1u);
    return (unsigned short)(u >> 16);
}

// ---------------------------------------------------------------------------
// Repack conv weights. wp2/wp3: (CO, 9, CI) bf16. wpL2: LRLC weights in the
// exact per-(s,cbk) LDS staging image (chunk = co*12 + slot, XOR swizzle
// baked), so the kernel's B staging is a pure linear copy.
// ---------------------------------------------------------------------------
__global__ __launch_bounds__(256) void repack_w(
    const float* __restrict__ c2w, const float* __restrict__ c3w,
    const float* __restrict__ bw,
    unsigned short* __restrict__ wp2, unsigned short* __restrict__ wp3,
    unsigned short* __restrict__ wpL2)
{
    int idx = blockIdx.x * 256 + threadIdx.x;
    if (idx < 18432) {                       // conv2: 64 x 9 x 32
        int co = idx / 288, rem = idx % 288, s = rem / 32, ci = rem % 32;
        wp2[idx] = f2bf(c2w[(co * 32 + ci) * 9 + s]);
    } else if (idx < 73728) {                // conv3: 96 x 9 x 64
        int i = idx - 18432;
        int co = i / 576, rem = i % 576, s = rem / 64, ci = rem % 64;
        wp3[i] = f2bf(c3w[(co * 64 + ci) * 9 + s]);
    } else if (idx < 516096) {               // lrlc staged: (9,4) x 1536 x 8
        int i = idx - 73728;
        int sb  = i / 12288;                 // s*4 + cbk
        int rem = i % 12288;
        int ch  = rem >> 3, e = rem & 7;
        int s = sb >> 2, cbk = sb & 3;
        int co = ch / 12, slot = ch % 12;    // co: local 0..127 = rank*32 + c
        int g  = slot ^ ((co >> 1) & 3);     // source ci-group
        int ci = g * 8 + e;
        int cog = (co >> 5) * 128 + cbk * 32 + (co & 31);
        wpL2[i] = f2bf(bw[(cog * 96 + ci) * 9 + s]);
    }
}

// ---------------------------------------------------------------------------
// conv1: CI=1 direct fp32, output NHWC bf16 (co fastest -> coalesced)
// ---------------------------------------------------------------------------
__global__ __launch_bounds__(256) void conv1_dir(
    const float* __restrict__ x,      // (64,1,128,128)
    const float* __restrict__ w,      // (32,1,3,3)
    const float* __restrict__ cbv, const float* __restrict__ gg,
    const float* __restrict__ bnb, const float* __restrict__ mm,
    const float* __restrict__ vv,
    unsigned short* __restrict__ out) // (64,64,64,32) NHWC bf16
{
    int idx = blockIdx.x * 256 + threadIdx.x;
    int co = idx & 31;
    int pw = (idx >> 5) & 63;
    int ph = (idx >> 11) & 63;
    int b  = idx >> 17;
    float scl = gg[co] * rsqrtf(vv[co] + EPS);
    float sh  = (cbv[co] - mm[co]) * scl + bnb[co];
    float wv[9];
    #pragma unroll
    for (int i = 0; i < 9; ++i) wv[i] = w[co * 9 + i];
    const float* xb = x + (size_t)b * 16384;
    int h0 = 2 * ph, w0 = 2 * pw;
    float p[4][4];
    #pragma unroll
    for (int dy = 0; dy < 4; ++dy) {
        int hy = h0 - 1 + dy;
        #pragma unroll
        for (int dx = 0; dx < 4; ++dx) {
            int wx = w0 - 1 + dx;
            p[dy][dx] = (hy >= 0 && hy < 128 && wx >= 0 && wx < 128)
                          ? xb[hy * 128 + wx] : 0.f;
        }
    }
    float a00 = 0.f, a01 = 0.f, a10 = 0.f, a11 = 0.f;
    #pragma unroll
    for (int ky = 0; ky < 3; ++ky)
        #pragma unroll
        for (int kx = 0; kx < 3; ++kx) {
            float wk = wv[ky * 3 + kx];
            a00 = fmaf(wk, p[ky][kx],         a00);
            a01 = fmaf(wk, p[ky][kx + 1],     a01);
            a10 = fmaf(wk, p[ky + 1][kx],     a10);
            a11 = fmaf(wk, p[ky + 1][kx + 1], a11);
        }
    float y0 = fmaf(a00, scl, sh), y1 = fmaf(a01, scl, sh);
    float y2 = fmaf(a10, scl, sh), y3 = fmaf(a11, scl, sh);
    float o = fmaxf(fmaxf(fmaxf(y0, y1), fmaxf(y2, y3)), 0.f);
    out[idx] = f2bf(o);
}

// ---------------------------------------------------------------------------
// Fused implicit-GEMM conv3x3 + BN + ReLU + pool2x2 via bf16 MFMA.
// ---------------------------------------------------------------------------
template<int CI, int CO, int W, int NWM, int NWN, bool ALLB,
         int SASH, int SAMK, int SBSH, int SBMK>
__global__ __launch_bounds__(256) void conv_mfma_pool(
    const unsigned short* __restrict__ xin,
    const unsigned short* __restrict__ wpk,
    const float* __restrict__ cbv, const float* __restrict__ gg,
    const float* __restrict__ bnb, const float* __restrict__ mm,
    const float* __restrict__ vv,
    unsigned short* __restrict__ out)
{
    constexpr int WT  = W + 2;
    constexpr int NFW = CO / 16 / NWN;
    constexpr int CG  = CI / 8;
    constexpr int ASZ = 4 * WT * CI * 2;
    constexpr int BSZ = (ALLB ? 9 : 1) * CO * CI * 2;
    constexpr int KSTEPS = CI / 32;
    constexpr int PH2 = W / 2;

    __shared__ __align__(16) unsigned char sm[ASZ + BSZ];

    const int tid = threadIdx.x;
    const int wave = tid >> 6, lane = tid & 63;
    const int quad = lane >> 4, col = lane & 15;
    const int wm = wave % NWM, wn = wave / NWM;

    const int hp = blockIdx.x % PH2;
    const int b  = blockIdx.x / PH2;

    constexpr int NCHA = 4 * WT * CG;
    for (int ch = tid; ch < NCHA; ch += 256) {
        int r    = ch / (WT * CG);
        int rem  = ch % (WT * CG);
        int wp   = rem / CG;
        int slot = rem % CG;
        int g = slot ^ ((wp >> SASH) & SAMK);
        int h = hp * 2 - 1 + r;
        int w = wp - 1;
        s16x8 val = {};
        if (h >= 0 && h < W && w >= 0 && w < W)
            val = *(const s16x8*)(xin + (((size_t)(b * W + h) * W + w) * CI + g * 8));
        *(s16x8*)(sm + ch * 16) = val;
    }
    if constexpr (ALLB) {
        constexpr int NCHB = CO * 9 * CG;
        for (int ch = tid; ch < NCHB; ch += 256) {
            int co   = ch / (9 * CG);
            int rem  = ch % (9 * CG);
            int s    = rem / CG;
            int slot = rem % CG;
            int g = slot ^ ((co >> SBSH) & SBMK);
            s16x8 val = *(const s16x8*)(wpk + ((co * 9 + s) * CI + g * 8));
            *(s16x8*)(sm + ASZ + ch * 16) = val;
        }
        __syncthreads();
    }

    f32x4 acc[2][NFW];
    #pragma unroll
    for (int i = 0; i < 2; ++i)
        #pragma unroll
        for (int j = 0; j < NFW; ++j) acc[i][j] = (f32x4){0.f, 0.f, 0.f, 0.f};

    #pragma unroll
    for (int s = 0; s < 9; ++s) {
        const int dy = s / 3, dx = s % 3;
        if constexpr (!ALLB) {
            __syncthreads();
            constexpr int NCHB = CO * CG;
            for (int ch = tid; ch < NCHB; ch += 256) {
                int co = ch / CG, slot = ch % CG;
                int g = slot ^ ((co >> SBSH) & SBMK);
                s16x8 val = *(const s16x8*)(wpk + ((co * 9 + s) * CI + g * 8));
                *(s16x8*)(sm + ASZ + ch * 16) = val;
            }
            __syncthreads();
        }
        #pragma unroll
        for (int kk = 0; kk < KSTEPS; ++kk) {
            const int g = kk * 4 + quad;
            s16x8 a[2];
            #pragma unroll
            for (int mi = 0; mi < 2; ++mi) {
                int wp = wm * 16 + col + dx;
                int r  = mi + dy;
                int addr = (r * WT + wp) * (CI * 2) + ((g ^ ((wp >> SASH) & SAMK)) << 4);
                a[mi] = *(const s16x8*)(sm + addr);
            }
            #pragma unroll
            for (int nf = 0; nf < NFW; ++nf) {
                int co_l = (wn * NFW + nf) * 16 + col;
                int row = ALLB ? (co_l * 9 + s) : co_l;
                int addr = ASZ + row * (CI * 2) + ((g ^ ((co_l >> SBSH) & SBMK)) << 4);
                s16x8 bf = *(const s16x8*)(sm + addr);
                acc[0][nf] = __builtin_amdgcn_mfma_f32_16x16x32_bf16(a[0], bf, acc[0][nf], 0, 0, 0);
                acc[1][nf] = __builtin_amdgcn_mfma_f32_16x16x32_bf16(a[1], bf, acc[1][nf], 0, 0, 0);
            }
        }
    }

    #pragma unroll
    for (int nf = 0; nf < NFW; ++nf) {
        int co = (wn * NFW + nf) * 16 + col;
        float scl = gg[co] * rsqrtf(vv[co] + EPS);
        float sh  = (cbv[co] - mm[co]) * scl + bnb[co];
        #pragma unroll
        for (int pr = 0; pr < 2; ++pr) {
            float y0 = fmaf(acc[0][nf][2 * pr],     scl, sh);
            float y1 = fmaf(acc[0][nf][2 * pr + 1], scl, sh);
            float y2 = fmaf(acc[1][nf][2 * pr],     scl, sh);
            float y3 = fmaf(acc[1][nf][2 * pr + 1], scl, sh);
            float o = fmaxf(fmaxf(fmaxf(y0, y1), fmaxf(y2, y3)), 0.f);
            int pw = wm * 8 + quad * 2 + pr;
            out[((size_t)(b * PH2 + hp) * PH2 + pw) * CO + co] = f2bf(o);
        }
    }
}

// ---------------------------------------------------------------------------
// LRLC v2: basis conv + softmax-rank combine + bias + relu + bf16 out.
//  - B staging is a LINEAR copy from pre-swizzled wpL2 (no address math)
//  - T14: next-phase B prefetched into regs before compute, written after
//  - 2x2 wave layout (wave = 64hw x 64co, N split by channel; ranks in-wave)
// Output: actB[b][k] bf16, k = c*256 + hw.
// ---------------------------------------------------------------------------
__global__ __launch_bounds__(256) void lrlc_mfma2(
    const unsigned short* __restrict__ xin,  // (64,16,16,96) bf16
    const unsigned short* __restrict__ wpk2, // (9,4,1536,8) staged bf16
    const float* __restrict__ bbias,         // (4,128)
    const float* __restrict__ cwh, const float* __restrict__ cww,
    unsigned short* __restrict__ actB)       // (64, 32768) bf16
{
    constexpr int CI = 96, WT = 18, NR = 10, CG = 12;
    constexpr int ASZ = NR * WT * CI * 2;    // 34560 B
    __shared__ __align__(16) unsigned char sm[ASZ + 128 * CI * 2];
    __shared__ float cwt[256][4];
    __shared__ unsigned short ldo[128][33];

    const int tid = threadIdx.x;
    const int wave = tid >> 6, lane = tid & 63;
    const int quad = lane >> 4, col = lane & 15;
    const int wm = wave & 1, wn = wave >> 1;

    const int cbk = blockIdx.x & 3;
    const int mb  = (blockIdx.x >> 2) & 1;
    const int b   = blockIdx.x >> 3;

    {   // softmax combining-weight table
        int h = tid >> 4, w = tid & 15;
        float e[4], mx = -1e30f;
        #pragma unroll
        for (int r = 0; r < 4; ++r) { e[r] = cwh[h * 4 + r] + cww[w * 4 + r]; mx = fmaxf(mx, e[r]); }
        float se = 0.f;
        #pragma unroll
        for (int r = 0; r < 4; ++r) { e[r] = expf(e[r] - mx); se += e[r]; }
        float inv = 1.f / se;
        #pragma unroll
        for (int r = 0; r < 4; ++r) cwt[tid][r] = e[r] * inv;
    }

    // stage A (proven R5 pattern)
    constexpr int NCHA = NR * WT * CG;  // 2160
    for (int ch = tid; ch < NCHA; ch += 256) {
        int r    = ch / (WT * CG);
        int rem  = ch % (WT * CG);
        int wp   = rem / CG, slot = rem % CG;
        int g = slot ^ ((wp >> 1) & 3);
        int h = mb * 8 + r - 1;
        int w = wp - 1;
        s16x8 val = {};
        if (h >= 0 && h < 16 && w >= 0 && w < 16)
            val = *(const s16x8*)(xin + (((size_t)(b * 16 + h) * 16 + w) * CI + g * 8));
        *(s16x8*)(sm + ch * 16) = val;
    }

    // prefetch B[0] into regs (linear copy from staged layout)
    s16x8 pre[6];
    #pragma unroll
    for (int it = 0; it < 6; ++it)
        pre[it] = *(const s16x8*)(wpk2 + (size_t)cbk * 12288 + (it * 256 + tid) * 8);

    __syncthreads();
    #pragma unroll
    for (int it = 0; it < 6; ++it)
        *(s16x8*)(sm + ASZ + (it * 256 + tid) * 16) = pre[it];
    __syncthreads();

    f32x4 acc[4][4];
    #pragma unroll
    for (int i = 0; i < 4; ++i)
        #pragma unroll
        for (int j = 0; j < 4; ++j) acc[i][j] = (f32x4){0.f, 0.f, 0.f, 0.f};

    for (int s = 0; s < 9; ++s) {
        const int dy = s / 3, dx = s % 3;
        // T14: issue next-phase B loads before compute (latency hides under MFMA)
        if (s < 8) {
            #pragma unroll
            for (int it = 0; it < 6; ++it)
                pre[it] = *(const s16x8*)(wpk2 +
                    (size_t)((s + 1) * 4 + cbk) * 12288 + (it * 256 + tid) * 8);
        }
        #pragma unroll
        for (int kk = 0; kk < 3; ++kk) {
            const int g = kk * 4 + quad;
            s16x8 a[4], bf[4];
            #pragma unroll
            for (int mi = 0; mi < 4; ++mi) {
                int mf = wm * 4 + mi;
                int r  = mf + dy;
                int wp = col + dx;
                int addr = (r * WT + wp) * (CI * 2) + ((g ^ ((wp >> 1) & 3)) << 4);
                a[mi] = *(const s16x8*)(sm + addr);
            }
            #pragma unroll
            for (int nf = 0; nf < 4; ++nf) {
                int co_loc = nf * 32 + wn * 16 + col;   // rank nf, channel wn*16+col
                int addr = ASZ + co_loc * (CI * 2) + ((g ^ ((co_loc >> 1) & 3)) << 4);
                bf[nf] = *(const s16x8*)(sm + addr);
            }
            #pragma unroll
            for (int mi = 0; mi < 4; ++mi)
                #pragma unroll
                for (int nf = 0; nf < 4; ++nf)
                    acc[mi][nf] = __builtin_amdgcn_mfma_f32_16x16x32_bf16(
                        a[mi], bf[nf], acc[mi][nf], 0, 0, 0);
        }
        __syncthreads();
        if (s < 8) {
            #pragma unroll
            for (int it = 0; it < 6; ++it)
                *(s16x8*)(sm + ASZ + (it * 256 + tid) * 16) = pre[it];
            __syncthreads();
        }
    }

    // rank combine + relu + bf16, stash to LDS for coalesced transpose-out
    {
        const int c_lo = wn * 16 + col;           // local channel 0..31
        const int cg   = cbk * 32 + c_lo;         // global channel
        float bb0 = bbias[cg],       bb1 = bbias[128 + cg],
              bb2 = bbias[256 + cg], bb3 = bbias[384 + cg];
        #pragma unroll
        for (int mi = 0; mi < 4; ++mi) {
            int mf = wm * 4 + mi;
            #pragma unroll
            for (int rg = 0; rg < 4; ++rg) {
                int hwl = mf * 16 + quad * 4 + rg;
                int hwg = mb * 128 + hwl;
                float o = cwt[hwg][0] * (acc[mi][0][rg] + bb0)
                        + cwt[hwg][1] * (acc[mi][1][rg] + bb1)
                        + cwt[hwg][2] * (acc[mi][2][rg] + bb2)
                        + cwt[hwg][3] * (acc[mi][3][rg] + bb3);
                ldo[hwl][c_lo] = f2bf(fmaxf(o, 0.f));
            }
        }
    }
    __syncthreads();
    {
        int cl = tid >> 3;   // 0..31
        int sg = tid & 7;    // 0..7
        size_t base = (size_t)b * 32768 + (cbk * 32 + cl) * 256 + mb * 128 + sg * 16;
        s16x8 v0, v1;
        #pragma unroll
        for (int i = 0; i < 8; ++i) v0[i] = (short)ldo[sg * 16 + i][cl];
        #pragma unroll
        for (int i = 0; i < 8; ++i) v1[i] = (short)ldo[sg * 16 + 8 + i][cl];
        *(s16x8*)(actB + base)     = v0;
        *(s16x8*)(actB + base + 8) = v1;
    }
}

// ---------------------------------------------------------------------------
// fc1 MFMA GEMM (R5-proven LDS operand path), K-split 64 for 2 blocks/CU.
// ---------------------------------------------------------------------------
__global__ __launch_bounds__(256) void fc1_lds(
    const unsigned short* __restrict__ actB, // (64, 32768) bf16
    const float* __restrict__ w,             // (512, 32768) f32
    float* __restrict__ partial)             // (64, 512, 64)
{
    __shared__ __align__(16) unsigned short Wl[64 * 256];
    __shared__ __align__(16) unsigned short Al[64 * 256];

    const int tid = threadIdx.x;
    const int wave = tid >> 6, lane = tid & 63;
    const int quad = lane >> 4, col = lane & 15;
    const int wm = wave & 1, wn = wave >> 1;
    const int jt = blockIdx.x & 7;
    const int ks = blockIdx.x >> 3;

    const int rt  = tid >> 2;     // staging row 0..63
    const int seg = tid & 3;      // 64-k segment 0..3

    f32x4 acc[2][2];
    #pragma unroll
    for (int i = 0; i < 2; ++i)
        #pragma unroll
        for (int j = 0; j < 2; ++j) acc[i][j] = (f32x4){0.f, 0.f, 0.f, 0.f};

    for (int c = 0; c < 2; ++c) {
        const int k0 = ks * 512 + c * 256;
        __syncthreads();
        const float* wsrc = w + (size_t)(jt * 64 + rt) * 32768 + k0 + seg * 64;
        #pragma unroll
        for (int u = 0; u < 8; ++u) {
            float4 f0 = *(const float4*)(wsrc + u * 8);
            float4 f1 = *(const float4*)(wsrc + u * 8 + 4);
            s16x8 v;
            v[0] = (short)f2bf(f0.x); v[1] = (short)f2bf(f0.y);
            v[2] = (short)f2bf(f0.z); v[3] = (short)f2bf(f0.w);
            v[4] = (short)f2bf(f1.x); v[5] = (short)f2bf(f1.y);
            v[6] = (short)f2bf(f1.z); v[7] = (short)f2bf(f1.w);
            int phys = (seg * 8 + u) ^ (rt & 7);
            *(s16x8*)(Wl + rt * 256 + phys * 8) = v;
        }
        const unsigned short* asrc = actB + (size_t)rt * 32768 + k0 + seg * 64;
        #pragma unroll
        for (int u = 0; u < 8; ++u) {
            s16x8 v = *(const s16x8*)(asrc + u * 8);
            int phys = (seg * 8 + u) ^ (rt & 7);
            *(s16x8*)(Al + rt * 256 + phys * 8) = v;
        }
        __syncthreads();
        #pragma unroll
        for (int kk = 0; kk < 8; ++kk) {
            const int gg = kk * 4 + quad;
            s16x8 a[2], bb[2];
            #pragma unroll
            for (int mf = 0; mf < 2; ++mf) {
                int j_l = wm * 32 + mf * 16 + col;
                a[mf] = *(const s16x8*)(Wl + j_l * 256 + ((gg ^ (j_l & 7)) << 3));
            }
            #pragma unroll
            for (int bg = 0; bg < 2; ++bg) {
                int b_l = wn * 32 + bg * 16 + col;
                bb[bg] = *(const s16x8*)(Al + b_l * 256 + ((gg ^ (b_l & 7)) << 3));
            }
            #pragma unroll
            for (int mf = 0; mf < 2; ++mf)
                #pragma unroll
                for (int bg = 0; bg < 2; ++bg)
                    acc[mf][bg] = __builtin_amdgcn_mfma_f32_16x16x32_bf16(
                        a[mf], bb[bg], acc[mf][bg], 0, 0, 0);
        }
    }
    #pragma unroll
    for (int mf = 0; mf < 2; ++mf)
        #pragma unroll
        for (int bg = 0; bg < 2; ++bg)
            #pragma unroll
            for (int r = 0; r < 4; ++r) {
                int j = jt * 64 + wm * 32 + mf * 16 + quad * 4 + r;
                int b = wn * 32 + bg * 16 + col;
                partial[((size_t)ks * 512 + j) * 64 + b] = acc[mf][bg][r];
            }
}

__global__ __launch_bounds__(256) void fc1_reduce4(
    const float* __restrict__ partial, const float* __restrict__ bias,
    float* __restrict__ out)             // (64,512)
{
    int idx = blockIdx.x * 256 + threadIdx.x;  // j*64 + b
    int b = idx & 63, j = idx >> 6;
    float a = bias[j];
    #pragma unroll 4
    for (int ks = 0; ks < 64; ++ks)
        a += partial[((size_t)ks * 512 + j) * 64 + b];
    out[b * 512 + j] = fmaxf(a, 0.f);
}

__global__ __launch_bounds__(256) void fc2_kernel(
    const float* __restrict__ x,    // (64, 512)
    const float* __restrict__ w,    // (10, 512)
    const float* __restrict__ bias,
    float* __restrict__ out)        // (64, 10)
{
    int idx = blockIdx.x * 256 + threadIdx.x;
    if (idx >= 640) return;
    int n = idx % 10, b = idx / 10;
    float a = bias[n];
    const float* xr = x + b * 512;
    const float* wr = w + n * 512;
    for (int j = 0; j < 512; ++j) a = fmaf(xr[j], wr[j], a);
    out[idx] = a;
}

// ---------------------------------------------------------------------------
extern "C" void kernel_launch(void* const* d_in, const int* in_sizes, int n_in,
                              void* d_out, int out_size, void* d_ws, size_t ws_size,
                              hipStream_t stream) {
    const float* x   = (const float*)d_in[0];
    const float* c1w = (const float*)d_in[1];  const float* c1b = (const float*)d_in[2];
    const float* b1g = (const float*)d_in[3];  const float* b1b = (const float*)d_in[4];
    const float* b1m = (const float*)d_in[5];  const float* b1v = (const float*)d_in[6];
    const float* c2w = (const float*)d_in[7];  const float* c2b = (const float*)d_in[8];
    const float* b2g = (const float*)d_in[9];  const float* b2b = (const float*)d_in[10];
    const float* b2m = (const float*)d_in[11]; const float* b2v = (const float*)d_in[12];
    const float* c3w = (const float*)d_in[13]; const float* c3b = (const float*)d_in[14];
    const float* b3g = (const float*)d_in[15]; const float* b3b = (const float*)d_in[16];
    const float* b3m = (const float*)d_in[17]; const float* b3v = (const float*)d_in[18];
    const float* bw  = (const float*)d_in[19]; const float* bb  = (const float*)d_in[20];
    const float* cwh = (const float*)d_in[21]; const float* cww = (const float*)d_in[22];
    const float* f1w = (const float*)d_in[23]; const float* f1b = (const float*)d_in[24];
    const float* f2w = (const float*)d_in[25]; const float* f2b = (const float*)d_in[26];
    float* out = (float*)d_out;

    char* ws = (char*)d_ws;
    // Liveness-ordered layout:
    unsigned short* act1 = (unsigned short*)(ws + 0);           // [0,16M)
    unsigned short* act2 = (unsigned short*)(ws + 16777216);    // [16M,24M)
    unsigned short* act3 = (unsigned short*)(ws + 0);           // [0,3M)   (act1 dead)
    unsigned short* actB = (unsigned short*)(ws + 4194304);     // [4M,8M)
    float*          part = (float*)(ws + 8388608);              // [8M,16M) 64x512x64
    float*          fc1o = (float*)(ws + 0);                    // [0,128K) (act3 dead)
    unsigned short* wp2  = (unsigned short*)(ws + 25165824);    //  36,864 B
    unsigned short* wp3  = (unsigned short*)(ws + 25202688);    // 110,592 B
    unsigned short* wpL2 = (unsigned short*)(ws + 25313280);    // 884,736 B

    repack_w<<<2016, 256, 0, stream>>>(c2w, c3w, bw, wp2, wp3, wpL2);

    conv1_dir<<<32768, 256, 0, stream>>>(x, c1w, c1b, b1g, b1b, b1m, b1v, act1);

    conv_mfma_pool<32, 64, 64, 4, 1, true, 1, 3, 1, 3>
        <<<2048, 256, 0, stream>>>(act1, wp2, c2b, b2g, b2b, b2m, b2v, act2);

    conv_mfma_pool<64, 96, 32, 2, 2, false, 0, 7, 0, 7>
        <<<1024, 256, 0, stream>>>(act2, wp3, c3b, b3g, b3b, b3m, b3v, act3);

    lrlc_mfma2<<<512, 256, 0, stream>>>(act3, wpL2, bb, cwh, cww, actB);

    fc1_lds<<<512, 256, 0, stream>>>(actB, f1w, part);
    fc1_reduce4<<<128, 256, 0, stream>>>(part, f1b, fc1o);
    fc2_kernel<<<3, 256, 0, stream>>>(fc1o, f2w, f2b, out);
}

// Round 7
// 142.219 us; speedup vs baseline: 21.1203x; 1.0833x over previous
//
#include <hip/hip_runtime.h>
#include <hip/hip_bf16.h>

#define EPS 1e-5f

typedef short s16x8 __attribute__((ext_vector_type(8)));
typedef float f32x4 __attribute__((ext_vector_type(4)));

__device__ __forceinline__ unsigned short f2bf(float f) {
    unsigned u = __float_as_uint(f);
    u += 0x7fffu + ((u >> 16) & 1u);
    return (unsigned short)(u >> 16);
}

// ---------------------------------------------------------------------------
// Repack conv weights. wp2/wp3: (CO, 9, CI) bf16. wpL2: LRLC weights in the
// exact per-(s,cbk) LDS staging image (chunk = co*12 + slot, XOR swizzle
// baked), so the kernel's B staging is a pure linear copy.
// ---------------------------------------------------------------------------
__global__ __launch_bounds__(256) void repack_w(
    const float* __restrict__ c2w, const float* __restrict__ c3w,
    const float* __restrict__ bw,
    unsigned short* __restrict__ wp2, unsigned short* __restrict__ wp3,
    unsigned short* __restrict__ wpL2)
{
    int idx = blockIdx.x * 256 + threadIdx.x;
    if (idx < 18432) {                       // conv2: 64 x 9 x 32
        int co = idx / 288, rem = idx % 288, s = rem / 32, ci = rem % 32;
        wp2[idx] = f2bf(c2w[(co * 32 + ci) * 9 + s]);
    } else if (idx < 73728) {                // conv3: 96 x 9 x 64
        int i = idx - 18432;
        int co = i / 576, rem = i % 576, s = rem / 64, ci = rem % 64;
        wp3[i] = f2bf(c3w[(co * 64 + ci) * 9 + s]);
    } else if (idx < 516096) {               // lrlc staged: (9,4) x 1536 x 8
        int i = idx - 73728;
        int sb  = i / 12288;                 // s*4 + cbk
        int rem = i % 12288;
        int ch  = rem >> 3, e = rem & 7;
        int s = sb >> 2, cbk = sb & 3;
        int co = ch / 12, slot = ch % 12;    // co: local 0..127 = rank*32 + c
        int g  = slot ^ ((co >> 1) & 3);     // source ci-group
        int ci = g * 8 + e;
        int cog = (co >> 5) * 128 + cbk * 32 + (co & 31);
        wpL2[i] = f2bf(bw[(cog * 96 + ci) * 9 + s]);
    }
}

// ---------------------------------------------------------------------------
// conv1 v2: block = (b, ph) output row; lane = pw (64); wave = co-chunk of 8.
// Each thread loads its 4x4 patch ONCE and reuses it for 8 channels.
// Weights/BN params wave-uniform -> scalar path. 16B contiguous store.
// ---------------------------------------------------------------------------
__global__ __launch_bounds__(256) void conv1_row(
    const float* __restrict__ x,      // (64,1,128,128)
    const float* __restrict__ w,      // (32,1,3,3)
    const float* __restrict__ cbv, const float* __restrict__ gg,
    const float* __restrict__ bnb, const float* __restrict__ mm,
    const float* __restrict__ vv,
    unsigned short* __restrict__ out) // (64,64,64,32) NHWC bf16
{
    const int bid = blockIdx.x;            // 4096 = 64 b x 64 ph
    const int b  = bid >> 6, ph = bid & 63;
    const int wavei = threadIdx.x >> 6, pw = threadIdx.x & 63;

    const float* xb = x + (size_t)b * 16384;
    const int h0 = 2 * ph, w0 = 2 * pw;
    float p[4][4];
    #pragma unroll
    for (int dy = 0; dy < 4; ++dy) {
        int hy = h0 - 1 + dy;
        bool hok = (hy >= 0) && (hy < 128);
        #pragma unroll
        for (int dx = 0; dx < 4; ++dx) {
            int wx = w0 - 1 + dx;
            p[dy][dx] = (hok && wx >= 0 && wx < 128) ? xb[hy * 128 + wx] : 0.f;
        }
    }

    s16x8 res;
    #pragma unroll
    for (int c8 = 0; c8 < 8; ++c8) {
        int co = wavei * 8 + c8;
        float scl = gg[co] * rsqrtf(vv[co] + EPS);
        float sh  = (cbv[co] - mm[co]) * scl + bnb[co];
        const float* wv = w + co * 9;
        float a00 = 0.f, a01 = 0.f, a10 = 0.f, a11 = 0.f;
        #pragma unroll
        for (int ky = 0; ky < 3; ++ky)
            #pragma unroll
            for (int kx = 0; kx < 3; ++kx) {
                float wk = wv[ky * 3 + kx];
                a00 = fmaf(wk, p[ky][kx],         a00);
                a01 = fmaf(wk, p[ky][kx + 1],     a01);
                a10 = fmaf(wk, p[ky + 1][kx],     a10);
                a11 = fmaf(wk, p[ky + 1][kx + 1], a11);
            }
        float y0 = fmaf(a00, scl, sh), y1 = fmaf(a01, scl, sh);
        float y2 = fmaf(a10, scl, sh), y3 = fmaf(a11, scl, sh);
        float o = fmaxf(fmaxf(fmaxf(y0, y1), fmaxf(y2, y3)), 0.f);
        res[c8] = (short)f2bf(o);
    }
    *(s16x8*)(out + (((size_t)bid) * 64 + pw) * 32 + wavei * 8) = res;
}

// ---------------------------------------------------------------------------
// Fused implicit-GEMM conv3x3 + BN + ReLU + pool2x2 via bf16 MFMA.
// ---------------------------------------------------------------------------
template<int CI, int CO, int W, int NWM, int NWN, bool ALLB,
         int SASH, int SAMK, int SBSH, int SBMK>
__global__ __launch_bounds__(256) void conv_mfma_pool(
    const unsigned short* __restrict__ xin,
    const unsigned short* __restrict__ wpk,
    const float* __restrict__ cbv, const float* __restrict__ gg,
    const float* __restrict__ bnb, const float* __restrict__ mm,
    const float* __restrict__ vv,
    unsigned short* __restrict__ out)
{
    constexpr int WT  = W + 2;
    constexpr int NFW = CO / 16 / NWN;
    constexpr int CG  = CI / 8;
    constexpr int ASZ = 4 * WT * CI * 2;
    constexpr int BSZ = (ALLB ? 9 : 1) * CO * CI * 2;
    constexpr int KSTEPS = CI / 32;
    constexpr int PH2 = W / 2;

    __shared__ __align__(16) unsigned char sm[ASZ + BSZ];

    const int tid = threadIdx.x;
    const int wave = tid >> 6, lane = tid & 63;
    const int quad = lane >> 4, col = lane & 15;
    const int wm = wave % NWM, wn = wave / NWM;

    const int hp = blockIdx.x % PH2;
    const int b  = blockIdx.x / PH2;

    constexpr int NCHA = 4 * WT * CG;
    for (int ch = tid; ch < NCHA; ch += 256) {
        int r    = ch / (WT * CG);
        int rem  = ch % (WT * CG);
        int wp   = rem / CG;
        int slot = rem % CG;
        int g = slot ^ ((wp >> SASH) & SAMK);
        int h = hp * 2 - 1 + r;
        int w = wp - 1;
        s16x8 val = {};
        if (h >= 0 && h < W && w >= 0 && w < W)
            val = *(const s16x8*)(xin + (((size_t)(b * W + h) * W + w) * CI + g * 8));
        *(s16x8*)(sm + ch * 16) = val;
    }
    if constexpr (ALLB) {
        constexpr int NCHB = CO * 9 * CG;
        for (int ch = tid; ch < NCHB; ch += 256) {
            int co   = ch / (9 * CG);
            int rem  = ch % (9 * CG);
            int s    = rem / CG;
            int slot = rem % CG;
            int g = slot ^ ((co >> SBSH) & SBMK);
            s16x8 val = *(const s16x8*)(wpk + ((co * 9 + s) * CI + g * 8));
            *(s16x8*)(sm + ASZ + ch * 16) = val;
        }
        __syncthreads();
    }

    f32x4 acc[2][NFW];
    #pragma unroll
    for (int i = 0; i < 2; ++i)
        #pragma unroll
        for (int j = 0; j < NFW; ++j) acc[i][j] = (f32x4){0.f, 0.f, 0.f, 0.f};

    #pragma unroll
    for (int s = 0; s < 9; ++s) {
        const int dy = s / 3, dx = s % 3;
        if constexpr (!ALLB) {
            __syncthreads();
            constexpr int NCHB = CO * CG;
            for (int ch = tid; ch < NCHB; ch += 256) {
                int co = ch / CG, slot = ch % CG;
                int g = slot ^ ((co >> SBSH) & SBMK);
                s16x8 val = *(const s16x8*)(wpk + ((co * 9 + s) * CI + g * 8));
                *(s16x8*)(sm + ASZ + ch * 16) = val;
            }
            __syncthreads();
        }
        #pragma unroll
        for (int kk = 0; kk < KSTEPS; ++kk) {
            const int g = kk * 4 + quad;
            s16x8 a[2];
            #pragma unroll
            for (int mi = 0; mi < 2; ++mi) {
                int wp = wm * 16 + col + dx;
                int r  = mi + dy;
                int addr = (r * WT + wp) * (CI * 2) + ((g ^ ((wp >> SASH) & SAMK)) << 4);
                a[mi] = *(const s16x8*)(sm + addr);
            }
            #pragma unroll
            for (int nf = 0; nf < NFW; ++nf) {
                int co_l = (wn * NFW + nf) * 16 + col;
                int row = ALLB ? (co_l * 9 + s) : co_l;
                int addr = ASZ + row * (CI * 2) + ((g ^ ((co_l >> SBSH) & SBMK)) << 4);
                s16x8 bf = *(const s16x8*)(sm + addr);
                acc[0][nf] = __builtin_amdgcn_mfma_f32_16x16x32_bf16(a[0], bf, acc[0][nf], 0, 0, 0);
                acc[1][nf] = __builtin_amdgcn_mfma_f32_16x16x32_bf16(a[1], bf, acc[1][nf], 0, 0, 0);
            }
        }
    }

    #pragma unroll
    for (int nf = 0; nf < NFW; ++nf) {
        int co = (wn * NFW + nf) * 16 + col;
        float scl = gg[co] * rsqrtf(vv[co] + EPS);
        float sh  = (cbv[co] - mm[co]) * scl + bnb[co];
        #pragma unroll
        for (int pr = 0; pr < 2; ++pr) {
            float y0 = fmaf(acc[0][nf][2 * pr],     scl, sh);
            float y1 = fmaf(acc[0][nf][2 * pr + 1], scl, sh);
            float y2 = fmaf(acc[1][nf][2 * pr],     scl, sh);
            float y3 = fmaf(acc[1][nf][2 * pr + 1], scl, sh);
            float o = fmaxf(fmaxf(fmaxf(y0, y1), fmaxf(y2, y3)), 0.f);
            int pw = wm * 8 + quad * 2 + pr;
            out[((size_t)(b * PH2 + hp) * PH2 + pw) * CO + co] = f2bf(o);
        }
    }
}

// ---------------------------------------------------------------------------
// LRLC v2: basis conv + softmax-rank combine + bias + relu + bf16 out.
// ---------------------------------------------------------------------------
__global__ __launch_bounds__(256) void lrlc_mfma2(
    const unsigned short* __restrict__ xin,  // (64,16,16,96) bf16
    const unsigned short* __restrict__ wpk2, // (9,4,1536,8) staged bf16
    const float* __restrict__ bbias,         // (4,128)
    const float* __restrict__ cwh, const float* __restrict__ cww,
    unsigned short* __restrict__ actB)       // (64, 32768) bf16
{
    constexpr int CI = 96, WT = 18, NR = 10, CG = 12;
    constexpr int ASZ = NR * WT * CI * 2;    // 34560 B
    __shared__ __align__(16) unsigned char sm[ASZ + 128 * CI * 2];
    __shared__ float cwt[256][4];
    __shared__ unsigned short ldo[128][33];

    const int tid = threadIdx.x;
    const int wave = tid >> 6, lane = tid & 63;
    const int quad = lane >> 4, col = lane & 15;
    const int wm = wave & 1, wn = wave >> 1;

    const int cbk = blockIdx.x & 3;
    const int mb  = (blockIdx.x >> 2) & 1;
    const int b   = blockIdx.x >> 3;

    {   // softmax combining-weight table
        int h = tid >> 4, w = tid & 15;
        float e[4], mx = -1e30f;
        #pragma unroll
        for (int r = 0; r < 4; ++r) { e[r] = cwh[h * 4 + r] + cww[w * 4 + r]; mx = fmaxf(mx, e[r]); }
        float se = 0.f;
        #pragma unroll
        for (int r = 0; r < 4; ++r) { e[r] = expf(e[r] - mx); se += e[r]; }
        float inv = 1.f / se;
        #pragma unroll
        for (int r = 0; r < 4; ++r) cwt[tid][r] = e[r] * inv;
    }

    constexpr int NCHA = NR * WT * CG;  // 2160
    for (int ch = tid; ch < NCHA; ch += 256) {
        int r    = ch / (WT * CG);
        int rem  = ch % (WT * CG);
        int wp   = rem / CG, slot = rem % CG;
        int g = slot ^ ((wp >> 1) & 3);
        int h = mb * 8 + r - 1;
        int w = wp - 1;
        s16x8 val = {};
        if (h >= 0 && h < 16 && w >= 0 && w < 16)
            val = *(const s16x8*)(xin + (((size_t)(b * 16 + h) * 16 + w) * CI + g * 8));
        *(s16x8*)(sm + ch * 16) = val;
    }

    s16x8 pre[6];
    #pragma unroll
    for (int it = 0; it < 6; ++it)
        pre[it] = *(const s16x8*)(wpk2 + (size_t)cbk * 12288 + (it * 256 + tid) * 8);

    __syncthreads();
    #pragma unroll
    for (int it = 0; it < 6; ++it)
        *(s16x8*)(sm + ASZ + (it * 256 + tid) * 16) = pre[it];
    __syncthreads();

    f32x4 acc[4][4];
    #pragma unroll
    for (int i = 0; i < 4; ++i)
        #pragma unroll
        for (int j = 0; j < 4; ++j) acc[i][j] = (f32x4){0.f, 0.f, 0.f, 0.f};

    for (int s = 0; s < 9; ++s) {
        const int dy = s / 3, dx = s % 3;
        if (s < 8) {
            #pragma unroll
            for (int it = 0; it < 6; ++it)
                pre[it] = *(const s16x8*)(wpk2 +
                    (size_t)((s + 1) * 4 + cbk) * 12288 + (it * 256 + tid) * 8);
        }
        #pragma unroll
        for (int kk = 0; kk < 3; ++kk) {
            const int g = kk * 4 + quad;
            s16x8 a[4], bf[4];
            #pragma unroll
            for (int mi = 0; mi < 4; ++mi) {
                int mf = wm * 4 + mi;
                int r  = mf + dy;
                int wp = col + dx;
                int addr = (r * WT + wp) * (CI * 2) + ((g ^ ((wp >> 1) & 3)) << 4);
                a[mi] = *(const s16x8*)(sm + addr);
            }
            #pragma unroll
            for (int nf = 0; nf < 4; ++nf) {
                int co_loc = nf * 32 + wn * 16 + col;
                int addr = ASZ + co_loc * (CI * 2) + ((g ^ ((co_loc >> 1) & 3)) << 4);
                bf[nf] = *(const s16x8*)(sm + addr);
            }
            #pragma unroll
            for (int mi = 0; mi < 4; ++mi)
                #pragma unroll
                for (int nf = 0; nf < 4; ++nf)
                    acc[mi][nf] = __builtin_amdgcn_mfma_f32_16x16x32_bf16(
                        a[mi], bf[nf], acc[mi][nf], 0, 0, 0);
        }
        __syncthreads();
        if (s < 8) {
            #pragma unroll
            for (int it = 0; it < 6; ++it)
                *(s16x8*)(sm + ASZ + (it * 256 + tid) * 16) = pre[it];
            __syncthreads();
        }
    }

    {
        const int c_lo = wn * 16 + col;
        const int cg   = cbk * 32 + c_lo;
        float bb0 = bbias[cg],       bb1 = bbias[128 + cg],
              bb2 = bbias[256 + cg], bb3 = bbias[384 + cg];
        #pragma unroll
        for (int mi = 0; mi < 4; ++mi) {
            int mf = wm * 4 + mi;
            #pragma unroll
            for (int rg = 0; rg < 4; ++rg) {
                int hwl = mf * 16 + quad * 4 + rg;
                int hwg = mb * 128 + hwl;
                float o = cwt[hwg][0] * (acc[mi][0][rg] + bb0)
                        + cwt[hwg][1] * (acc[mi][1][rg] + bb1)
                        + cwt[hwg][2] * (acc[mi][2][rg] + bb2)
                        + cwt[hwg][3] * (acc[mi][3][rg] + bb3);
                ldo[hwl][c_lo] = f2bf(fmaxf(o, 0.f));
            }
        }
    }
    __syncthreads();
    {
        int cl = tid >> 3;
        int sg = tid & 7;
        size_t base = (size_t)b * 32768 + (cbk * 32 + cl) * 256 + mb * 128 + sg * 16;
        s16x8 v0, v1;
        #pragma unroll
        for (int i = 0; i < 8; ++i) v0[i] = (short)ldo[sg * 16 + i][cl];
        #pragma unroll
        for (int i = 0; i < 8; ++i) v1[i] = (short)ldo[sg * 16 + 8 + i][cl];
        *(s16x8*)(actB + base)     = v0;
        *(s16x8*)(actB + base + 8) = v1;
    }
}

// ---------------------------------------------------------------------------
// fc1 MFMA GEMM (R5-proven LDS operand path), K-split 64 for 2 blocks/CU.
// ---------------------------------------------------------------------------
__global__ __launch_bounds__(256) void fc1_lds(
    const unsigned short* __restrict__ actB, // (64, 32768) bf16
    const float* __restrict__ w,             // (512, 32768) f32
    float* __restrict__ partial)             // (64, 512, 64)
{
    __shared__ __align__(16) unsigned short Wl[64 * 256];
    __shared__ __align__(16) unsigned short Al[64 * 256];

    const int tid = threadIdx.x;
    const int wave = tid >> 6, lane = tid & 63;
    const int quad = lane >> 4, col = lane & 15;
    const int wm = wave & 1, wn = wave >> 1;
    const int jt = blockIdx.x & 7;
    const int ks = blockIdx.x >> 3;

    const int rt  = tid >> 2;
    const int seg = tid & 3;

    f32x4 acc[2][2];
    #pragma unroll
    for (int i = 0; i < 2; ++i)
        #pragma unroll
        for (int j = 0; j < 2; ++j) acc[i][j] = (f32x4){0.f, 0.f, 0.f, 0.f};

    for (int c = 0; c < 2; ++c) {
        const int k0 = ks * 512 + c * 256;
        __syncthreads();
        const float* wsrc = w + (size_t)(jt * 64 + rt) * 32768 + k0 + seg * 64;
        #pragma unroll
        for (int u = 0; u < 8; ++u) {
            float4 f0 = *(const float4*)(wsrc + u * 8);
            float4 f1 = *(const float4*)(wsrc + u * 8 + 4);
            s16x8 v;
            v[0] = (short)f2bf(f0.x); v[1] = (short)f2bf(f0.y);
            v[2] = (short)f2bf(f0.z); v[3] = (short)f2bf(f0.w);
            v[4] = (short)f2bf(f1.x); v[5] = (short)f2bf(f1.y);
            v[6] = (short)f2bf(f1.z); v[7] = (short)f2bf(f1.w);
            int phys = (seg * 8 + u) ^ (rt & 7);
            *(s16x8*)(Wl + rt * 256 + phys * 8) = v;
        }
        const unsigned short* asrc = actB + (size_t)rt * 32768 + k0 + seg * 64;
        #pragma unroll
        for (int u = 0; u < 8; ++u) {
            s16x8 v = *(const s16x8*)(asrc + u * 8);
            int phys = (seg * 8 + u) ^ (rt & 7);
            *(s16x8*)(Al + rt * 256 + phys * 8) = v;
        }
        __syncthreads();
        #pragma unroll
        for (int kk = 0; kk < 8; ++kk) {
            const int gg = kk * 4 + quad;
            s16x8 a[2], bb[2];
            #pragma unroll
            for (int mf = 0; mf < 2; ++mf) {
                int j_l = wm * 32 + mf * 16 + col;
                a[mf] = *(const s16x8*)(Wl + j_l * 256 + ((gg ^ (j_l & 7)) << 3));
            }
            #pragma unroll
            for (int bg = 0; bg < 2; ++bg) {
                int b_l = wn * 32 + bg * 16 + col;
                bb[bg] = *(const s16x8*)(Al + b_l * 256 + ((gg ^ (b_l & 7)) << 3));
            }
            #pragma unroll
            for (int mf = 0; mf < 2; ++mf)
                #pragma unroll
                for (int bg = 0; bg < 2; ++bg)
                    acc[mf][bg] = __builtin_amdgcn_mfma_f32_16x16x32_bf16(
                        a[mf], bb[bg], acc[mf][bg], 0, 0, 0);
        }
    }
    #pragma unroll
    for (int mf = 0; mf < 2; ++mf)
        #pragma unroll
        for (int bg = 0; bg < 2; ++bg)
            #pragma unroll
            for (int r = 0; r < 4; ++r) {
                int j = jt * 64 + wm * 32 + mf * 16 + quad * 4 + r;
                int b = wn * 32 + bg * 16 + col;
                partial[((size_t)ks * 512 + j) * 64 + b] = acc[mf][bg][r];
            }
}

__global__ __launch_bounds__(256) void fc1_reduce4(
    const float* __restrict__ partial, const float* __restrict__ bias,
    float* __restrict__ out)             // (64,512)
{
    int idx = blockIdx.x * 256 + threadIdx.x;
    int b = idx & 63, j = idx >> 6;
    float a = bias[j];
    #pragma unroll 4
    for (int ks = 0; ks < 64; ++ks)
        a += partial[((size_t)ks * 512 + j) * 64 + b];
    out[b * 512 + j] = fmaxf(a, 0.f);
}

__global__ __launch_bounds__(256) void fc2_kernel(
    const float* __restrict__ x,    // (64, 512)
    const float* __restrict__ w,    // (10, 512)
    const float* __restrict__ bias,
    float* __restrict__ out)        // (64, 10)
{
    int idx = blockIdx.x * 256 + threadIdx.x;
    if (idx >= 640) return;
    int n = idx % 10, b = idx / 10;
    float a = bias[n];
    const float* xr = x + b * 512;
    const float* wr = w + n * 512;
    for (int j = 0; j < 512; ++j) a = fmaf(xr[j], wr[j], a);
    out[idx] = a;
}

// ---------------------------------------------------------------------------
extern "C" void kernel_launch(void* const* d_in, const int* in_sizes, int n_in,
                              void* d_out, int out_size, void* d_ws, size_t ws_size,
                              hipStream_t stream) {
    const float* x   = (const float*)d_in[0];
    const float* c1w = (const float*)d_in[1];  const float* c1b = (const float*)d_in[2];
    const float* b1g = (const float*)d_in[3];  const float* b1b = (const float*)d_in[4];
    const float* b1m = (const float*)d_in[5];  const float* b1v = (const float*)d_in[6];
    const float* c2w = (const float*)d_in[7];  const float* c2b = (const float*)d_in[8];
    const float* b2g = (const float*)d_in[9];  const float* b2b = (const float*)d_in[10];
    const float* b2m = (const float*)d_in[11]; const float* b2v = (const float*)d_in[12];
    const float* c3w = (const float*)d_in[13]; const float* c3b = (const float*)d_in[14];
    const float* b3g = (const float*)d_in[15]; const float* b3b = (const float*)d_in[16];
    const float* b3m = (const float*)d_in[17]; const float* b3v = (const float*)d_in[18];
    const float* bw  = (const float*)d_in[19]; const float* bb  = (const float*)d_in[20];
    const float* cwh = (const float*)d_in[21]; const float* cww = (const float*)d_in[22];
    const float* f1w = (const float*)d_in[23]; const float* f1b = (const float*)d_in[24];
    const float* f2w = (const float*)d_in[25]; const float* f2b = (const float*)d_in[26];
    float* out = (float*)d_out;

    char* ws = (char*)d_ws;
    unsigned short* act1 = (unsigned short*)(ws + 0);           // [0,16M)
    unsigned short* act2 = (unsigned short*)(ws + 16777216);    // [16M,24M)
    unsigned short* act3 = (unsigned short*)(ws + 0);           // [0,3M)   (act1 dead)
    unsigned short* actB = (unsigned short*)(ws + 4194304);     // [4M,8M)
    float*          part = (float*)(ws + 8388608);              // [8M,16M) 64x512x64
    float*          fc1o = (float*)(ws + 0);                    // [0,128K) (act3 dead)
    unsigned short* wp2  = (unsigned short*)(ws + 25165824);    //  36,864 B
    unsigned short* wp3  = (unsigned short*)(ws + 25202688);    // 110,592 B
    unsigned short* wpL2 = (unsigned short*)(ws + 25313280);    // 884,736 B

    repack_w<<<2016, 256, 0, stream>>>(c2w, c3w, bw, wp2, wp3, wpL2);

    conv1_row<<<4096, 256, 0, stream>>>(x, c1w, c1b, b1g, b1b, b1m, b1v, act1);

    conv_mfma_pool<32, 64, 64, 4, 1, true, 1, 3, 1, 3>
        <<<2048, 256, 0, stream>>>(act1, wp2, c2b, b2g, b2b, b2m, b2v, act2);

    conv_mfma_pool<64, 96, 32, 2, 2, false, 0, 7, 0, 7>
        <<<1024, 256, 0, stream>>>(act2, wp3, c3b, b3g, b3b, b3m, b3v, act3);

    lrlc_mfma2<<<512, 256, 0, stream>>>(act3, wpL2, bb, cwh, cww, actB);

    fc1_lds<<<512, 256, 0, stream>>>(actB, f1w, part);
    fc1_reduce4<<<128, 256, 0, stream>>>(part, f1b, fc1o);
    fc2_kernel<<<3, 256, 0, stream>>>(fc1o, f2w, f2b, out);
}

// Round 8
// 140.020 us; speedup vs baseline: 21.4521x; 1.0157x over previous
//
#include <hip/hip_runtime.h>
#include <hip/hip_bf16.h>

#define EPS 1e-5f

typedef short s16x8 __attribute__((ext_vector_type(8)));
typedef float f32x4 __attribute__((ext_vector_type(4)));

__device__ __forceinline__ unsigned short f2bf(float f) {
    unsigned u = __float_as_uint(f);
    u += 0x7fffu + ((u >> 16) & 1u);
    return (unsigned short)(u >> 16);
}

// ---------------------------------------------------------------------------
// Repack conv weights. wp2/wp3: (CO, 9, CI) bf16. wpL2: LRLC weights in the
// exact per-(s,cbk) LDS staging image (chunk = co*12 + slot, XOR swizzle
// baked), so the kernel's B staging is a pure linear copy.
// ---------------------------------------------------------------------------
__global__ __launch_bounds__(256) void repack_w(
    const float* __restrict__ c2w, const float* __restrict__ c3w,
    const float* __restrict__ bw,
    unsigned short* __restrict__ wp2, unsigned short* __restrict__ wp3,
    unsigned short* __restrict__ wpL2)
{
    int idx = blockIdx.x * 256 + threadIdx.x;
    if (idx < 18432) {                       // conv2: 64 x 9 x 32
        int co = idx / 288, rem = idx % 288, s = rem / 32, ci = rem % 32;
        wp2[idx] = f2bf(c2w[(co * 32 + ci) * 9 + s]);
    } else if (idx < 73728) {                // conv3: 96 x 9 x 64
        int i = idx - 18432;
        int co = i / 576, rem = i % 576, s = rem / 64, ci = rem % 64;
        wp3[i] = f2bf(c3w[(co * 64 + ci) * 9 + s]);
    } else if (idx < 516096) {               // lrlc staged: (9,4) x 1536 x 8
        int i = idx - 73728;
        int sb  = i / 12288;                 // s*4 + cbk
        int rem = i % 12288;
        int ch  = rem >> 3, e = rem & 7;
        int s = sb >> 2, cbk = sb & 3;
        int co = ch / 12, slot = ch % 12;    // co: local 0..127 = rank*32 + c
        int g  = slot ^ ((co >> 1) & 3);     // source ci-group
        int ci = g * 8 + e;
        int cog = (co >> 5) * 128 + cbk * 32 + (co & 31);
        wpL2[i] = f2bf(bw[(cog * 96 + ci) * 9 + s]);
    }
}

// ---------------------------------------------------------------------------
// conv1: block = (b, ph) output row; lane = pw (64); wave = co-chunk of 8.
// ---------------------------------------------------------------------------
__global__ __launch_bounds__(256) void conv1_row(
    const float* __restrict__ x,      // (64,1,128,128)
    const float* __restrict__ w,      // (32,1,3,3)
    const float* __restrict__ cbv, const float* __restrict__ gg,
    const float* __restrict__ bnb, const float* __restrict__ mm,
    const float* __restrict__ vv,
    unsigned short* __restrict__ out) // (64,64,64,32) NHWC bf16
{
    const int bid = blockIdx.x;            // 4096 = 64 b x 64 ph
    const int b  = bid >> 6, ph = bid & 63;
    const int wavei = threadIdx.x >> 6, pw = threadIdx.x & 63;

    const float* xb = x + (size_t)b * 16384;
    const int h0 = 2 * ph, w0 = 2 * pw;
    float p[4][4];
    #pragma unroll
    for (int dy = 0; dy < 4; ++dy) {
        int hy = h0 - 1 + dy;
        bool hok = (hy >= 0) && (hy < 128);
        #pragma unroll
        for (int dx = 0; dx < 4; ++dx) {
            int wx = w0 - 1 + dx;
            p[dy][dx] = (hok && wx >= 0 && wx < 128) ? xb[hy * 128 + wx] : 0.f;
        }
    }

    s16x8 res;
    #pragma unroll
    for (int c8 = 0; c8 < 8; ++c8) {
        int co = wavei * 8 + c8;
        float scl = gg[co] * rsqrtf(vv[co] + EPS);
        float sh  = (cbv[co] - mm[co]) * scl + bnb[co];
        const float* wv = w + co * 9;
        float a00 = 0.f, a01 = 0.f, a10 = 0.f, a11 = 0.f;
        #pragma unroll
        for (int ky = 0; ky < 3; ++ky)
            #pragma unroll
            for (int kx = 0; kx < 3; ++kx) {
                float wk = wv[ky * 3 + kx];
                a00 = fmaf(wk, p[ky][kx],         a00);
                a01 = fmaf(wk, p[ky][kx + 1],     a01);
                a10 = fmaf(wk, p[ky + 1][kx],     a10);
                a11 = fmaf(wk, p[ky + 1][kx + 1], a11);
            }
        float y0 = fmaf(a00, scl, sh), y1 = fmaf(a01, scl, sh);
        float y2 = fmaf(a10, scl, sh), y3 = fmaf(a11, scl, sh);
        float o = fmaxf(fmaxf(fmaxf(y0, y1), fmaxf(y2, y3)), 0.f);
        res[c8] = (short)f2bf(o);
    }
    *(s16x8*)(out + (((size_t)bid) * 64 + pw) * 32 + wavei * 8) = res;
}

// ---------------------------------------------------------------------------
// Fused implicit-GEMM conv3x3 + BN + ReLU + pool2x2 via bf16 MFMA.
// ---------------------------------------------------------------------------
template<int CI, int CO, int W, int NWM, int NWN, bool ALLB,
         int SASH, int SAMK, int SBSH, int SBMK>
__global__ __launch_bounds__(256) void conv_mfma_pool(
    const unsigned short* __restrict__ xin,
    const unsigned short* __restrict__ wpk,
    const float* __restrict__ cbv, const float* __restrict__ gg,
    const float* __restrict__ bnb, const float* __restrict__ mm,
    const float* __restrict__ vv,
    unsigned short* __restrict__ out)
{
    constexpr int WT  = W + 2;
    constexpr int NFW = CO / 16 / NWN;
    constexpr int CG  = CI / 8;
    constexpr int ASZ = 4 * WT * CI * 2;
    constexpr int BSZ = (ALLB ? 9 : 1) * CO * CI * 2;
    constexpr int KSTEPS = CI / 32;
    constexpr int PH2 = W / 2;

    __shared__ __align__(16) unsigned char sm[ASZ + BSZ];

    const int tid = threadIdx.x;
    const int wave = tid >> 6, lane = tid & 63;
    const int quad = lane >> 4, col = lane & 15;
    const int wm = wave % NWM, wn = wave / NWM;

    const int hp = blockIdx.x % PH2;
    const int b  = blockIdx.x / PH2;

    constexpr int NCHA = 4 * WT * CG;
    for (int ch = tid; ch < NCHA; ch += 256) {
        int r    = ch / (WT * CG);
        int rem  = ch % (WT * CG);
        int wp   = rem / CG;
        int slot = rem % CG;
        int g = slot ^ ((wp >> SASH) & SAMK);
        int h = hp * 2 - 1 + r;
        int w = wp - 1;
        s16x8 val = {};
        if (h >= 0 && h < W && w >= 0 && w < W)
            val = *(const s16x8*)(xin + (((size_t)(b * W + h) * W + w) * CI + g * 8));
        *(s16x8*)(sm + ch * 16) = val;
    }
    if constexpr (ALLB) {
        constexpr int NCHB = CO * 9 * CG;
        for (int ch = tid; ch < NCHB; ch += 256) {
            int co   = ch / (9 * CG);
            int rem  = ch % (9 * CG);
            int s    = rem / CG;
            int slot = rem % CG;
            int g = slot ^ ((co >> SBSH) & SBMK);
            s16x8 val = *(const s16x8*)(wpk + ((co * 9 + s) * CI + g * 8));
            *(s16x8*)(sm + ASZ + ch * 16) = val;
        }
        __syncthreads();
    }

    f32x4 acc[2][NFW];
    #pragma unroll
    for (int i = 0; i < 2; ++i)
        #pragma unroll
        for (int j = 0; j < NFW; ++j) acc[i][j] = (f32x4){0.f, 0.f, 0.f, 0.f};

    #pragma unroll
    for (int s = 0; s < 9; ++s) {
        const int dy = s / 3, dx = s % 3;
        if constexpr (!ALLB) {
            __syncthreads();
            constexpr int NCHB = CO * CG;
            for (int ch = tid; ch < NCHB; ch += 256) {
                int co = ch / CG, slot = ch % CG;
                int g = slot ^ ((co >> SBSH) & SBMK);
                s16x8 val = *(const s16x8*)(wpk + ((co * 9 + s) * CI + g * 8));
                *(s16x8*)(sm + ASZ + ch * 16) = val;
            }
            __syncthreads();
        }
        #pragma unroll
        for (int kk = 0; kk < KSTEPS; ++kk) {
            const int g = kk * 4 + quad;
            s16x8 a[2];
            #pragma unroll
            for (int mi = 0; mi < 2; ++mi) {
                int wp = wm * 16 + col + dx;
                int r  = mi + dy;
                int addr = (r * WT + wp) * (CI * 2) + ((g ^ ((wp >> SASH) & SAMK)) << 4);
                a[mi] = *(const s16x8*)(sm + addr);
            }
            #pragma unroll
            for (int nf = 0; nf < NFW; ++nf) {
                int co_l = (wn * NFW + nf) * 16 + col;
                int row = ALLB ? (co_l * 9 + s) : co_l;
                int addr = ASZ + row * (CI * 2) + ((g ^ ((co_l >> SBSH) & SBMK)) << 4);
                s16x8 bf = *(const s16x8*)(sm + addr);
                acc[0][nf] = __builtin_amdgcn_mfma_f32_16x16x32_bf16(a[0], bf, acc[0][nf], 0, 0, 0);
                acc[1][nf] = __builtin_amdgcn_mfma_f32_16x16x32_bf16(a[1], bf, acc[1][nf], 0, 0, 0);
            }
        }
    }

    #pragma unroll
    for (int nf = 0; nf < NFW; ++nf) {
        int co = (wn * NFW + nf) * 16 + col;
        float scl = gg[co] * rsqrtf(vv[co] + EPS);
        float sh  = (cbv[co] - mm[co]) * scl + bnb[co];
        #pragma unroll
        for (int pr = 0; pr < 2; ++pr) {
            float y0 = fmaf(acc[0][nf][2 * pr],     scl, sh);
            float y1 = fmaf(acc[0][nf][2 * pr + 1], scl, sh);
            float y2 = fmaf(acc[1][nf][2 * pr],     scl, sh);
            float y3 = fmaf(acc[1][nf][2 * pr + 1], scl, sh);
            float o = fmaxf(fmaxf(fmaxf(y0, y1), fmaxf(y2, y3)), 0.f);
            int pw = wm * 8 + quad * 2 + pr;
            out[((size_t)(b * PH2 + hp) * PH2 + pw) * CO + co] = f2bf(o);
        }
    }
}

// ---------------------------------------------------------------------------
// LRLC v3: 512 threads / 8 waves. wave = (wm M-half, g c-group, rp rank-pair).
// Each wave: 4 M-frags x 2 ranks. Partial rank-combine -> f32 LDS plane
// (aliased over the A region, dead after last MFMA); final sum + relu + bf16
// in the transpose-out. B staging: linear copy from pre-swizzled wpL2 with
// T14 register prefetch.
// ---------------------------------------------------------------------------
__global__ __launch_bounds__(512) void lrlc_mfma3(
    const unsigned short* __restrict__ xin,  // (64,16,16,96) bf16
    const unsigned short* __restrict__ wpk2, // (9,4,1536,8) staged bf16
    const float* __restrict__ bbias,         // (4,128)
    const float* __restrict__ cwh, const float* __restrict__ cww,
    unsigned short* __restrict__ actB)       // (64, 32768) bf16
{
    constexpr int CI = 96, WT = 18, NR = 10, CG = 12;
    constexpr int ASZ = NR * WT * CI * 2;    // 34560 B
    constexpr int BSZ = 128 * CI * 2;        // 24576 B
    __shared__ __align__(16) unsigned char sm[ASZ + BSZ];  // ldo f32[2][128][33] aliases sm
    __shared__ float cwt[256][4];

    const int tid = threadIdx.x;
    const int wave = tid >> 6, lane = tid & 63;
    const int quad = lane >> 4, col = lane & 15;
    const int wm = wave & 1;            // M half
    const int g  = (wave >> 1) & 1;     // c group of 16
    const int rp = wave >> 2;           // rank pair 0..1

    const int cbk = blockIdx.x & 3;
    const int mb  = (blockIdx.x >> 2) & 1;
    const int b   = blockIdx.x >> 3;

    if (tid < 256) {   // softmax combining-weight table
        int h = tid >> 4, w = tid & 15;
        float e[4], mx = -1e30f;
        #pragma unroll
        for (int r = 0; r < 4; ++r) { e[r] = cwh[h * 4 + r] + cww[w * 4 + r]; mx = fmaxf(mx, e[r]); }
        float se = 0.f;
        #pragma unroll
        for (int r = 0; r < 4; ++r) { e[r] = expf(e[r] - mx); se += e[r]; }
        float inv = 1.f / se;
        #pragma unroll
        for (int r = 0; r < 4; ++r) cwt[tid][r] = e[r] * inv;
    }

    constexpr int NCHA = NR * WT * CG;  // 2160
    for (int ch = tid; ch < NCHA; ch += 512) {
        int r    = ch / (WT * CG);
        int rem  = ch % (WT * CG);
        int wp   = rem / CG, slot = rem % CG;
        int gg_ = slot ^ ((wp >> 1) & 3);
        int h = mb * 8 + r - 1;
        int w = wp - 1;
        s16x8 val = {};
        if (h >= 0 && h < 16 && w >= 0 && w < 16)
            val = *(const s16x8*)(xin + (((size_t)(b * 16 + h) * 16 + w) * CI + gg_ * 8));
        *(s16x8*)(sm + ch * 16) = val;
    }

    s16x8 pre[3];
    #pragma unroll
    for (int it = 0; it < 3; ++it)
        pre[it] = *(const s16x8*)(wpk2 + (size_t)cbk * 12288 + (it * 512 + tid) * 8);

    __syncthreads();
    #pragma unroll
    for (int it = 0; it < 3; ++it)
        *(s16x8*)(sm + ASZ + (it * 512 + tid) * 16) = pre[it];
    __syncthreads();

    f32x4 acc[4][2];
    #pragma unroll
    for (int i = 0; i < 4; ++i)
        #pragma unroll
        for (int j = 0; j < 2; ++j) acc[i][j] = (f32x4){0.f, 0.f, 0.f, 0.f};

    for (int s = 0; s < 9; ++s) {
        const int dy = s / 3, dx = s % 3;
        if (s < 8) {   // T14 prefetch
            #pragma unroll
            for (int it = 0; it < 3; ++it)
                pre[it] = *(const s16x8*)(wpk2 +
                    (size_t)((s + 1) * 4 + cbk) * 12288 + (it * 512 + tid) * 8);
        }
        #pragma unroll
        for (int kk = 0; kk < 3; ++kk) {
            const int gg = kk * 4 + quad;
            s16x8 a[4], bf[2];
            #pragma unroll
            for (int mi = 0; mi < 4; ++mi) {
                int mf = wm * 4 + mi;
                int r  = mf + dy;
                int wp = col + dx;
                int addr = (r * WT + wp) * (CI * 2) + ((gg ^ ((wp >> 1) & 3)) << 4);
                a[mi] = *(const s16x8*)(sm + addr);
            }
            #pragma unroll
            for (int j = 0; j < 2; ++j) {
                int co_loc = (rp * 2 + j) * 32 + g * 16 + col;
                int addr = ASZ + co_loc * (CI * 2) + ((gg ^ ((co_loc >> 1) & 3)) << 4);
                bf[j] = *(const s16x8*)(sm + addr);
            }
            #pragma unroll
            for (int mi = 0; mi < 4; ++mi)
                #pragma unroll
                for (int j = 0; j < 2; ++j)
                    acc[mi][j] = __builtin_amdgcn_mfma_f32_16x16x32_bf16(
                        a[mi], bf[j], acc[mi][j], 0, 0, 0);
        }
        __syncthreads();
        if (s < 8) {
            #pragma unroll
            for (int it = 0; it < 3; ++it)
                *(s16x8*)(sm + ASZ + (it * 512 + tid) * 16) = pre[it];
            __syncthreads();
        }
    }

    // partial rank-pair combine -> f32 LDS (aliased over A region, now dead)
    float* ldo = (float*)sm;   // [2][128][33]
    {
        const int c_lo = g * 16 + col;
        const int cg   = cbk * 32 + c_lo;
        float bbA = bbias[(rp * 2 + 0) * 128 + cg];
        float bbB = bbias[(rp * 2 + 1) * 128 + cg];
        #pragma unroll
        for (int mi = 0; mi < 4; ++mi) {
            int mf = wm * 4 + mi;
            #pragma unroll
            for (int rg = 0; rg < 4; ++rg) {
                int hwl = mf * 16 + quad * 4 + rg;
                int hwg = mb * 128 + hwl;
                float o = cwt[hwg][rp * 2]     * (acc[mi][0][rg] + bbA)
                        + cwt[hwg][rp * 2 + 1] * (acc[mi][1][rg] + bbB);
                ldo[(rp * 128 + hwl) * 33 + c_lo] = o;
            }
        }
    }
    __syncthreads();
    {   // sum pairs + relu + bf16, coalesced transpose write-out
        int cl = tid >> 4;   // 0..31
        int sg = tid & 15;   // 0..15
        size_t base = (size_t)b * 32768 + (cbk * 32 + cl) * 256 + mb * 128 + sg * 8;
        s16x8 v;
        #pragma unroll
        for (int i = 0; i < 8; ++i) {
            int hw = sg * 8 + i;
            float o = ldo[hw * 33 + cl] + ldo[(128 + hw) * 33 + cl];
            v[i] = (short)f2bf(fmaxf(o, 0.f));
        }
        *(s16x8*)(actB + base) = v;
    }
}

// ---------------------------------------------------------------------------
// fc1 MFMA GEMM (R5-proven LDS operand path) + T14 register prefetch:
// both chunks' W/act loaded into regs early; regs->LDS after the barrier.
// ---------------------------------------------------------------------------
__global__ __launch_bounds__(256) void fc1_lds(
    const unsigned short* __restrict__ actB, // (64, 32768) bf16
    const float* __restrict__ w,             // (512, 32768) f32
    float* __restrict__ partial)             // (64, 512, 64)
{
    __shared__ __align__(16) unsigned short Wl[64 * 256];
    __shared__ __align__(16) unsigned short Al[64 * 256];

    const int tid = threadIdx.x;
    const int wave = tid >> 6, lane = tid & 63;
    const int quad = lane >> 4, col = lane & 15;
    const int wm = wave & 1, wn = wave >> 1;
    const int jt = blockIdx.x & 7;
    const int ks = blockIdx.x >> 3;

    const int rt  = tid >> 2;
    const int seg = tid & 3;

    const float* wsrc = w + (size_t)(jt * 64 + rt) * 32768 + ks * 512 + seg * 64;
    const unsigned short* asrc = actB + (size_t)rt * 32768 + ks * 512 + seg * 64;

    f32x4 acc[2][2];
    #pragma unroll
    for (int i = 0; i < 2; ++i)
        #pragma unroll
        for (int j = 0; j < 2; ++j) acc[i][j] = (f32x4){0.f, 0.f, 0.f, 0.f};

    // prefetch chunk 0 into regs
    float4 pw0[8], pw1[8]; s16x8 pa[8];
    #pragma unroll
    for (int u = 0; u < 8; ++u) {
        pw0[u] = *(const float4*)(wsrc + u * 8);
        pw1[u] = *(const float4*)(wsrc + u * 8 + 4);
        pa[u]  = *(const s16x8*)(asrc + u * 8);
    }

    #pragma unroll
    for (int c = 0; c < 2; ++c) {
        // write staged regs -> LDS
        #pragma unroll
        for (int u = 0; u < 8; ++u) {
            s16x8 v;
            v[0] = (short)f2bf(pw0[u].x); v[1] = (short)f2bf(pw0[u].y);
            v[2] = (short)f2bf(pw0[u].z); v[3] = (short)f2bf(pw0[u].w);
            v[4] = (short)f2bf(pw1[u].x); v[5] = (short)f2bf(pw1[u].y);
            v[6] = (short)f2bf(pw1[u].z); v[7] = (short)f2bf(pw1[u].w);
            int phys = (seg * 8 + u) ^ (rt & 7);
            *(s16x8*)(Wl + rt * 256 + phys * 8) = v;
            *(s16x8*)(Al + rt * 256 + phys * 8) = pa[u];
        }
        __syncthreads();
        if (c == 0) {   // T14: issue chunk-1 loads before chunk-0 compute
            #pragma unroll
            for (int u = 0; u < 8; ++u) {
                pw0[u] = *(const float4*)(wsrc + 256 + u * 8);
                pw1[u] = *(const float4*)(wsrc + 256 + u * 8 + 4);
                pa[u]  = *(const s16x8*)(asrc + 256 + u * 8);
            }
        }
        #pragma unroll
        for (int kk = 0; kk < 8; ++kk) {
            const int gg = kk * 4 + quad;
            s16x8 a[2], bb[2];
            #pragma unroll
            for (int mf = 0; mf < 2; ++mf) {
                int j_l = wm * 32 + mf * 16 + col;
                a[mf] = *(const s16x8*)(Wl + j_l * 256 + ((gg ^ (j_l & 7)) << 3));
            }
            #pragma unroll
            for (int bg = 0; bg < 2; ++bg) {
                int b_l = wn * 32 + bg * 16 + col;
                bb[bg] = *(const s16x8*)(Al + b_l * 256 + ((gg ^ (b_l & 7)) << 3));
            }
            #pragma unroll
            for (int mf = 0; mf < 2; ++mf)
                #pragma unroll
                for (int bg = 0; bg < 2; ++bg)
                    acc[mf][bg] = __builtin_amdgcn_mfma_f32_16x16x32_bf16(
                        a[mf], bb[bg], acc[mf][bg], 0, 0, 0);
        }
        __syncthreads();
    }
    #pragma unroll
    for (int mf = 0; mf < 2; ++mf)
        #pragma unroll
        for (int bg = 0; bg < 2; ++bg)
            #pragma unroll
            for (int r = 0; r < 4; ++r) {
                int j = jt * 64 + wm * 32 + mf * 16 + quad * 4 + r;
                int b = wn * 32 + bg * 16 + col;
                partial[((size_t)ks * 512 + j) * 64 + b] = acc[mf][bg][r];
            }
}

__global__ __launch_bounds__(256) void fc1_reduce4(
    const float* __restrict__ partial, const float* __restrict__ bias,
    float* __restrict__ out)             // (64,512)
{
    int idx = blockIdx.x * 256 + threadIdx.x;
    int b = idx & 63, j = idx >> 6;
    float a = bias[j];
    #pragma unroll 8
    for (int ks = 0; ks < 64; ++ks)
        a += partial[((size_t)ks * 512 + j) * 64 + b];
    out[b * 512 + j] = fmaxf(a, 0.f);
}

__global__ __launch_bounds__(256) void fc2_kernel(
    const float* __restrict__ x,    // (64, 512)
    const float* __restrict__ w,    // (10, 512)
    const float* __restrict__ bias,
    float* __restrict__ out)        // (64, 10)
{
    int idx = blockIdx.x * 256 + threadIdx.x;
    if (idx >= 640) return;
    int n = idx % 10, b = idx / 10;
    float a = bias[n];
    const float* xr = x + b * 512;
    const float* wr = w + n * 512;
    for (int j = 0; j < 512; ++j) a = fmaf(xr[j], wr[j], a);
    out[idx] = a;
}

// ---------------------------------------------------------------------------
extern "C" void kernel_launch(void* const* d_in, const int* in_sizes, int n_in,
                              void* d_out, int out_size, void* d_ws, size_t ws_size,
                              hipStream_t stream) {
    const float* x   = (const float*)d_in[0];
    const float* c1w = (const float*)d_in[1];  const float* c1b = (const float*)d_in[2];
    const float* b1g = (const float*)d_in[3];  const float* b1b = (const float*)d_in[4];
    const float* b1m = (const float*)d_in[5];  const float* b1v = (const float*)d_in[6];
    const float* c2w = (const float*)d_in[7];  const float* c2b = (const float*)d_in[8];
    const float* b2g = (const float*)d_in[9];  const float* b2b = (const float*)d_in[10];
    const float* b2m = (const float*)d_in[11]; const float* b2v = (const float*)d_in[12];
    const float* c3w = (const float*)d_in[13]; const float* c3b = (const float*)d_in[14];
    const float* b3g = (const float*)d_in[15]; const float* b3b = (const float*)d_in[16];
    const float* b3m = (const float*)d_in[17]; const float* b3v = (const float*)d_in[18];
    const float* bw  = (const float*)d_in[19]; const float* bb  = (const float*)d_in[20];
    const float* cwh = (const float*)d_in[21]; const float* cww = (const float*)d_in[22];
    const float* f1w = (const float*)d_in[23]; const float* f1b = (const float*)d_in[24];
    const float* f2w = (const float*)d_in[25]; const float* f2b = (const float*)d_in[26];
    float* out = (float*)d_out;

    char* ws = (char*)d_ws;
    unsigned short* act1 = (unsigned short*)(ws + 0);           // [0,16M)
    unsigned short* act2 = (unsigned short*)(ws + 16777216);    // [16M,24M)
    unsigned short* act3 = (unsigned short*)(ws + 0);           // [0,3M)   (act1 dead)
    unsigned short* actB = (unsigned short*)(ws + 4194304);     // [4M,8M)
    float*          part = (float*)(ws + 8388608);              // [8M,16M) 64x512x64
    float*          fc1o = (float*)(ws + 0);                    // [0,128K) (act3 dead)
    unsigned short* wp2  = (unsigned short*)(ws + 25165824);    //  36,864 B
    unsigned short* wp3  = (unsigned short*)(ws + 25202688);    // 110,592 B
    unsigned short* wpL2 = (unsigned short*)(ws + 25313280);    // 884,736 B

    repack_w<<<2016, 256, 0, stream>>>(c2w, c3w, bw, wp2, wp3, wpL2);

    conv1_row<<<4096, 256, 0, stream>>>(x, c1w, c1b, b1g, b1b, b1m, b1v, act1);

    conv_mfma_pool<32, 64, 64, 4, 1, true, 1, 3, 1, 3>
        <<<2048, 256, 0, stream>>>(act1, wp2, c2b, b2g, b2b, b2m, b2v, act2);

    conv_mfma_pool<64, 96, 32, 2, 2, false, 0, 7, 0, 7>
        <<<1024, 256, 0, stream>>>(act2, wp3, c3b, b3g, b3b, b3m, b3v, act3);

    lrlc_mfma3<<<512, 512, 0, stream>>>(act3, wpL2, bb, cwh, cww, actB);

    fc1_lds<<<512, 256, 0, stream>>>(actB, f1w, part);
    fc1_reduce4<<<128, 256, 0, stream>>>(part, f1b, fc1o);
    fc2_kernel<<<3, 256, 0, stream>>>(fc1o, f2w, f2b, out);
}

// Round 9
// 136.190 us; speedup vs baseline: 22.0553x; 1.0281x over previous
//
#include <hip/hip_runtime.h>
#include <hip/hip_bf16.h>

#define EPS 1e-5f

typedef short s16x8 __attribute__((ext_vector_type(8)));
typedef float f32x4 __attribute__((ext_vector_type(4)));

__device__ __forceinline__ unsigned short f2bf(float f) {
    unsigned u = __float_as_uint(f);
    u += 0x7fffu + ((u >> 16) & 1u);
    return (unsigned short)(u >> 16);
}

// ---------------------------------------------------------------------------
// Repack conv weights. wp2/wp3: (CO, 9, CI) bf16. wpL3: LRLC weights in MFMA
// fragment order [s][cbk][g][rp][j][kk][lane][8e] so the kernel loads B-frags
// as wave-coalesced 1KB global reads (no LDS staging, no barriers).
// ---------------------------------------------------------------------------
__global__ __launch_bounds__(256) void repack_w(
    const float* __restrict__ c2w, const float* __restrict__ c3w,
    const float* __restrict__ bw,
    unsigned short* __restrict__ wp2, unsigned short* __restrict__ wp3,
    unsigned short* __restrict__ wpL3)
{
    int idx = blockIdx.x * 256 + threadIdx.x;
    if (idx < 18432) {                       // conv2: 64 x 9 x 32
        int co = idx / 288, rem = idx % 288, s = rem / 32, ci = rem % 32;
        wp2[idx] = f2bf(c2w[(co * 32 + ci) * 9 + s]);
    } else if (idx < 73728) {                // conv3: 96 x 9 x 64
        int i = idx - 18432;
        int co = i / 576, rem = i % 576, s = rem / 64, ci = rem % 64;
        wp3[i] = f2bf(c3w[(co * 64 + ci) * 9 + s]);
    } else if (idx < 516096) {               // lrlc frag-order: 442368 elems
        int i = idx - 73728;
        int e    = i & 7;
        int lane = (i >> 3) & 63;
        int fk   = i >> 9;            // t*3 + kk
        int kk   = fk % 3;
        int t    = fk / 3;            // = (((s*4+cbk)*2+g)*2+rp)*2+j
        int j    = t & 1;
        int rp   = (t >> 1) & 1;
        int g    = (t >> 2) & 1;
        int cbk  = (t >> 3) & 3;
        int s    = t >> 5;
        int col = lane & 15, quad = lane >> 4;
        int cog = (rp * 2 + j) * 128 + cbk * 32 + g * 16 + col;
        int ci  = (kk * 4 + quad) * 8 + e;
        wpL3[i] = f2bf(bw[(cog * 96 + ci) * 9 + s]);
    }
}

// ---------------------------------------------------------------------------
// conv1: block = (b, ph) output row; lane = pw (64); wave = co-chunk of 8.
// ---------------------------------------------------------------------------
__global__ __launch_bounds__(256) void conv1_row(
    const float* __restrict__ x,      // (64,1,128,128)
    const float* __restrict__ w,      // (32,1,3,3)
    const float* __restrict__ cbv, const float* __restrict__ gg,
    const float* __restrict__ bnb, const float* __restrict__ mm,
    const float* __restrict__ vv,
    unsigned short* __restrict__ out) // (64,64,64,32) NHWC bf16
{
    const int bid = blockIdx.x;            // 4096 = 64 b x 64 ph
    const int b  = bid >> 6, ph = bid & 63;
    const int wavei = threadIdx.x >> 6, pw = threadIdx.x & 63;

    const float* xb = x + (size_t)b * 16384;
    const int h0 = 2 * ph, w0 = 2 * pw;
    float p[4][4];
    #pragma unroll
    for (int dy = 0; dy < 4; ++dy) {
        int hy = h0 - 1 + dy;
        bool hok = (hy >= 0) && (hy < 128);
        #pragma unroll
        for (int dx = 0; dx < 4; ++dx) {
            int wx = w0 - 1 + dx;
            p[dy][dx] = (hok && wx >= 0 && wx < 128) ? xb[hy * 128 + wx] : 0.f;
        }
    }

    s16x8 res;
    #pragma unroll
    for (int c8 = 0; c8 < 8; ++c8) {
        int co = wavei * 8 + c8;
        float scl = gg[co] * rsqrtf(vv[co] + EPS);
        float sh  = (cbv[co] - mm[co]) * scl + bnb[co];
        const float* wv = w + co * 9;
        float a00 = 0.f, a01 = 0.f, a10 = 0.f, a11 = 0.f;
        #pragma unroll
        for (int ky = 0; ky < 3; ++ky)
            #pragma unroll
            for (int kx = 0; kx < 3; ++kx) {
                float wk = wv[ky * 3 + kx];
                a00 = fmaf(wk, p[ky][kx],         a00);
                a01 = fmaf(wk, p[ky][kx + 1],     a01);
                a10 = fmaf(wk, p[ky + 1][kx],     a10);
                a11 = fmaf(wk, p[ky + 1][kx + 1], a11);
            }
        float y0 = fmaf(a00, scl, sh), y1 = fmaf(a01, scl, sh);
        float y2 = fmaf(a10, scl, sh), y3 = fmaf(a11, scl, sh);
        float o = fmaxf(fmaxf(fmaxf(y0, y1), fmaxf(y2, y3)), 0.f);
        res[c8] = (short)f2bf(o);
    }
    *(s16x8*)(out + (((size_t)bid) * 64 + pw) * 32 + wavei * 8) = res;
}

// ---------------------------------------------------------------------------
// Fused implicit-GEMM conv3x3 + BN + ReLU + pool2x2 via bf16 MFMA.
// blockIdx remapped XCD-aware: each XCD owns a contiguous hp-range per b.
// ---------------------------------------------------------------------------
template<int CI, int CO, int W, int NWM, int NWN, bool ALLB,
         int SASH, int SAMK, int SBSH, int SBMK>
__global__ __launch_bounds__(256) void conv_mfma_pool(
    const unsigned short* __restrict__ xin,
    const unsigned short* __restrict__ wpk,
    const float* __restrict__ cbv, const float* __restrict__ gg,
    const float* __restrict__ bnb, const float* __restrict__ mm,
    const float* __restrict__ vv,
    unsigned short* __restrict__ out)
{
    constexpr int WT  = W + 2;
    constexpr int NFW = CO / 16 / NWN;
    constexpr int CG  = CI / 8;
    constexpr int ASZ = 4 * WT * CI * 2;
    constexpr int BSZ = (ALLB ? 9 : 1) * CO * CI * 2;
    constexpr int KSTEPS = CI / 32;
    constexpr int PH2 = W / 2;
    constexpr int HPX = PH2 / 8;   // hp per XCD per b

    __shared__ __align__(16) unsigned char sm[ASZ + BSZ];

    const int tid = threadIdx.x;
    const int wave = tid >> 6, lane = tid & 63;
    const int quad = lane >> 4, col = lane & 15;
    const int wm = wave % NWM, wn = wave / NWM;

    const int xcd  = blockIdx.x & 7;
    const int slot = blockIdx.x >> 3;
    const int hp = xcd * HPX + (slot % HPX);
    const int b  = slot / HPX;

    constexpr int NCHA = 4 * WT * CG;
    for (int ch = tid; ch < NCHA; ch += 256) {
        int r    = ch / (WT * CG);
        int rem  = ch % (WT * CG);
        int wp   = rem / CG;
        int slot_ = rem % CG;
        int g = slot_ ^ ((wp >> SASH) & SAMK);
        int h = hp * 2 - 1 + r;
        int w = wp - 1;
        s16x8 val = {};
        if (h >= 0 && h < W && w >= 0 && w < W)
            val = *(const s16x8*)(xin + (((size_t)(b * W + h) * W + w) * CI + g * 8));
        *(s16x8*)(sm + ch * 16) = val;
    }
    if constexpr (ALLB) {
        constexpr int NCHB = CO * 9 * CG;
        for (int ch = tid; ch < NCHB; ch += 256) {
            int co   = ch / (9 * CG);
            int rem  = ch % (9 * CG);
            int s    = rem / CG;
            int slot_ = rem % CG;
            int g = slot_ ^ ((co >> SBSH) & SBMK);
            s16x8 val = *(const s16x8*)(wpk + ((co * 9 + s) * CI + g * 8));
            *(s16x8*)(sm + ASZ + ch * 16) = val;
        }
        __syncthreads();
    }

    f32x4 acc[2][NFW];
    #pragma unroll
    for (int i = 0; i < 2; ++i)
        #pragma unroll
        for (int j = 0; j < NFW; ++j) acc[i][j] = (f32x4){0.f, 0.f, 0.f, 0.f};

    #pragma unroll
    for (int s = 0; s < 9; ++s) {
        const int dy = s / 3, dx = s % 3;
        if constexpr (!ALLB) {
            __syncthreads();
            constexpr int NCHB = CO * CG;
            for (int ch = tid; ch < NCHB; ch += 256) {
                int co = ch / CG, slot_ = ch % CG;
                int g = slot_ ^ ((co >> SBSH) & SBMK);
                s16x8 val = *(const s16x8*)(wpk + ((co * 9 + s) * CI + g * 8));
                *(s16x8*)(sm + ASZ + ch * 16) = val;
            }
            __syncthreads();
        }
        #pragma unroll
        for (int kk = 0; kk < KSTEPS; ++kk) {
            const int g = kk * 4 + quad;
            s16x8 a[2];
            #pragma unroll
            for (int mi = 0; mi < 2; ++mi) {
                int wp = wm * 16 + col + dx;
                int r  = mi + dy;
                int addr = (r * WT + wp) * (CI * 2) + ((g ^ ((wp >> SASH) & SAMK)) << 4);
                a[mi] = *(const s16x8*)(sm + addr);
            }
            #pragma unroll
            for (int nf = 0; nf < NFW; ++nf) {
                int co_l = (wn * NFW + nf) * 16 + col;
                int row = ALLB ? (co_l * 9 + s) : co_l;
                int addr = ASZ + row * (CI * 2) + ((g ^ ((co_l >> SBSH) & SBMK)) << 4);
                s16x8 bf = *(const s16x8*)(sm + addr);
                acc[0][nf] = __builtin_amdgcn_mfma_f32_16x16x32_bf16(a[0], bf, acc[0][nf], 0, 0, 0);
                acc[1][nf] = __builtin_amdgcn_mfma_f32_16x16x32_bf16(a[1], bf, acc[1][nf], 0, 0, 0);
            }
        }
    }

    #pragma unroll
    for (int nf = 0; nf < NFW; ++nf) {
        int co = (wn * NFW + nf) * 16 + col;
        float scl = gg[co] * rsqrtf(vv[co] + EPS);
        float sh  = (cbv[co] - mm[co]) * scl + bnb[co];
        #pragma unroll
        for (int pr = 0; pr < 2; ++pr) {
            float y0 = fmaf(acc[0][nf][2 * pr],     scl, sh);
            float y1 = fmaf(acc[0][nf][2 * pr + 1], scl, sh);
            float y2 = fmaf(acc[1][nf][2 * pr],     scl, sh);
            float y3 = fmaf(acc[1][nf][2 * pr + 1], scl, sh);
            float o = fmaxf(fmaxf(fmaxf(y0, y1), fmaxf(y2, y3)), 0.f);
            int pw = wm * 8 + quad * 2 + pr;
            out[((size_t)(b * PH2 + hp) * PH2 + pw) * CO + co] = f2bf(o);
        }
    }
}

// ---------------------------------------------------------------------------
// LRLC v4: B operand loaded per-wave directly from fragment-ordered wpL3
// (6 coalesced 1KB loads per shift, L2-hot) -> NO B-LDS, NO in-loop barriers
// (3 barriers total vs 19). A in LDS (proven). 8 waves: (wm, g, rp).
// ---------------------------------------------------------------------------
__global__ __launch_bounds__(512) void lrlc_mfma4(
    const unsigned short* __restrict__ xin,  // (64,16,16,96) bf16
    const unsigned short* __restrict__ wpk3, // frag-ordered (442368)
    const float* __restrict__ bbias,         // (4,128)
    const float* __restrict__ cwh, const float* __restrict__ cww,
    unsigned short* __restrict__ actB)       // (64, 32768) bf16
{
    constexpr int CI = 96, WT = 18, NR = 10, CG = 12;
    constexpr int ASZ = NR * WT * CI * 2;    // 34560 B (ldo f32[2][128][33]=33792 aliases)
    __shared__ __align__(16) unsigned char sm[ASZ];
    __shared__ float cwt[256][4];

    const int tid = threadIdx.x;
    const int wave = tid >> 6, lane = tid & 63;
    const int quad = lane >> 4, col = lane & 15;
    const int wm = wave & 1;            // M half
    const int g  = (wave >> 1) & 1;     // c group of 16
    const int rp = wave >> 2;           // rank pair 0..1

    const int cbk = blockIdx.x & 3;
    const int mb  = (blockIdx.x >> 2) & 1;
    const int b   = blockIdx.x >> 3;

    if (tid < 256) {   // softmax combining-weight table
        int h = tid >> 4, w = tid & 15;
        float e[4], mx = -1e30f;
        #pragma unroll
        for (int r = 0; r < 4; ++r) { e[r] = cwh[h * 4 + r] + cww[w * 4 + r]; mx = fmaxf(mx, e[r]); }
        float se = 0.f;
        #pragma unroll
        for (int r = 0; r < 4; ++r) { e[r] = expf(e[r] - mx); se += e[r]; }
        float inv = 1.f / se;
        #pragma unroll
        for (int r = 0; r < 4; ++r) cwt[tid][r] = e[r] * inv;
    }

    constexpr int NCHA = NR * WT * CG;  // 2160
    for (int ch = tid; ch < NCHA; ch += 512) {
        int r    = ch / (WT * CG);
        int rem  = ch % (WT * CG);
        int wp   = rem / CG, slot = rem % CG;
        int gg_ = slot ^ ((wp >> 1) & 3);
        int h = mb * 8 + r - 1;
        int w = wp - 1;
        s16x8 val = {};
        if (h >= 0 && h < 16 && w >= 0 && w < 16)
            val = *(const s16x8*)(xin + (((size_t)(b * 16 + h) * 16 + w) * CI + gg_ * 8));
        *(s16x8*)(sm + ch * 16) = val;
    }
    __syncthreads();

    f32x4 acc[4][2];
    #pragma unroll
    for (int i = 0; i < 4; ++i)
        #pragma unroll
        for (int j = 0; j < 2; ++j) acc[i][j] = (f32x4){0.f, 0.f, 0.f, 0.f};

    // wave-uniform base into frag-ordered table: t = (((s*4+cbk)*2+g)*2+rp)*2+j
    const int tbase = ((cbk * 2 + g) * 2 + rp);   // add s*32 per shift, *2+j
    for (int s = 0; s < 9; ++s) {
        const int dy = s / 3, dx = s % 3;
        s16x8 bf[2][3];
        #pragma unroll
        for (int j = 0; j < 2; ++j)
            #pragma unroll
            for (int kk = 0; kk < 3; ++kk) {
                int fidx = ((s * 32 + tbase * 2 + j) * 3 + kk) * 512 + lane * 8;
                bf[j][kk] = *(const s16x8*)(wpk3 + fidx);
            }
        #pragma unroll
        for (int kk = 0; kk < 3; ++kk) {
            const int gg = kk * 4 + quad;
            s16x8 a[4];
            #pragma unroll
            for (int mi = 0; mi < 4; ++mi) {
                int mf = wm * 4 + mi;
                int r  = mf + dy;
                int wp = col + dx;
                int addr = (r * WT + wp) * (CI * 2) + ((gg ^ ((wp >> 1) & 3)) << 4);
                a[mi] = *(const s16x8*)(sm + addr);
            }
            #pragma unroll
            for (int mi = 0; mi < 4; ++mi)
                #pragma unroll
                for (int j = 0; j < 2; ++j)
                    acc[mi][j] = __builtin_amdgcn_mfma_f32_16x16x32_bf16(
                        a[mi], bf[j][kk], acc[mi][j], 0, 0, 0);
        }
    }
    __syncthreads();   // A reads done before aliasing ldo over sm

    float* ldo = (float*)sm;   // [2][128][33]
    {
        const int c_lo = g * 16 + col;
        const int cg   = cbk * 32 + c_lo;
        float bbA = bbias[(rp * 2 + 0) * 128 + cg];
        float bbB = bbias[(rp * 2 + 1) * 128 + cg];
        #pragma unroll
        for (int mi = 0; mi < 4; ++mi) {
            int mf = wm * 4 + mi;
            #pragma unroll
            for (int rg = 0; rg < 4; ++rg) {
                int hwl = mf * 16 + quad * 4 + rg;
                int hwg = mb * 128 + hwl;
                float o = cwt[hwg][rp * 2]     * (acc[mi][0][rg] + bbA)
                        + cwt[hwg][rp * 2 + 1] * (acc[mi][1][rg] + bbB);
                ldo[(rp * 128 + hwl) * 33 + c_lo] = o;
            }
        }
    }
    __syncthreads();
    {   // sum rank-pairs + relu + bf16, coalesced transpose write-out
        int cl = tid >> 4;   // 0..31
        int sg = tid & 15;   // 0..15
        size_t base = (size_t)b * 32768 + (cbk * 32 + cl) * 256 + mb * 128 + sg * 8;
        s16x8 v;
        #pragma unroll
        for (int i = 0; i < 8; ++i) {
            int hw = sg * 8 + i;
            float o = ldo[hw * 33 + cl] + ldo[(128 + hw) * 33 + cl];
            v[i] = (short)f2bf(fmaxf(o, 0.f));
        }
        *(s16x8*)(actB + base) = v;
    }
}

// ---------------------------------------------------------------------------
// fc1 MFMA GEMM (R5-proven LDS operand path) + T14 register prefetch.
// XCD-aware mapping: each XCD owns a contiguous ks range so the 8 same-ks
// blocks (sharing a 64KB act chunk) hit the same L2.
// ---------------------------------------------------------------------------
__global__ __launch_bounds__(256) void fc1_lds(
    const unsigned short* __restrict__ actB, // (64, 32768) bf16
    const float* __restrict__ w,             // (512, 32768) f32
    float* __restrict__ partial)             // (64, 512, 64)
{
    __shared__ __align__(16) unsigned short Wl[64 * 256];
    __shared__ __align__(16) unsigned short Al[64 * 256];

    const int tid = threadIdx.x;
    const int wave = tid >> 6, lane = tid & 63;
    const int quad = lane >> 4, col = lane & 15;
    const int wm = wave & 1, wn = wave >> 1;
    const int xcd  = blockIdx.x & 7;
    const int slot = blockIdx.x >> 3;
    const int ks = xcd * 8 + (slot >> 3);
    const int jt = slot & 7;

    const int rt  = tid >> 2;
    const int seg = tid & 3;

    const float* wsrc = w + (size_t)(jt * 64 + rt) * 32768 + ks * 512 + seg * 64;
    const unsigned short* asrc = actB + (size_t)rt * 32768 + ks * 512 + seg * 64;

    f32x4 acc[2][2];
    #pragma unroll
    for (int i = 0; i < 2; ++i)
        #pragma unroll
        for (int j = 0; j < 2; ++j) acc[i][j] = (f32x4){0.f, 0.f, 0.f, 0.f};

    float4 pw0[8], pw1[8]; s16x8 pa[8];
    #pragma unroll
    for (int u = 0; u < 8; ++u) {
        pw0[u] = *(const float4*)(wsrc + u * 8);
        pw1[u] = *(const float4*)(wsrc + u * 8 + 4);
        pa[u]  = *(const s16x8*)(asrc + u * 8);
    }

    #pragma unroll
    for (int c = 0; c < 2; ++c) {
        #pragma unroll
        for (int u = 0; u < 8; ++u) {
            s16x8 v;
            v[0] = (short)f2bf(pw0[u].x); v[1] = (short)f2bf(pw0[u].y);
            v[2] = (short)f2bf(pw0[u].z); v[3] = (short)f2bf(pw0[u].w);
            v[4] = (short)f2bf(pw1[u].x); v[5] = (short)f2bf(pw1[u].y);
            v[6] = (short)f2bf(pw1[u].z); v[7] = (short)f2bf(pw1[u].w);
            int phys = (seg * 8 + u) ^ (rt & 7);
            *(s16x8*)(Wl + rt * 256 + phys * 8) = v;
            *(s16x8*)(Al + rt * 256 + phys * 8) = pa[u];
        }
        __syncthreads();
        if (c == 0) {
            #pragma unroll
            for (int u = 0; u < 8; ++u) {
                pw0[u] = *(const float4*)(wsrc + 256 + u * 8);
                pw1[u] = *(const float4*)(wsrc + 256 + u * 8 + 4);
                pa[u]  = *(const s16x8*)(asrc + 256 + u * 8);
            }
        }
        #pragma unroll
        for (int kk = 0; kk < 8; ++kk) {
            const int gg = kk * 4 + quad;
            s16x8 a[2], bb[2];
            #pragma unroll
            for (int mf = 0; mf < 2; ++mf) {
                int j_l = wm * 32 + mf * 16 + col;
                a[mf] = *(const s16x8*)(Wl + j_l * 256 + ((gg ^ (j_l & 7)) << 3));
            }
            #pragma unroll
            for (int bg = 0; bg < 2; ++bg) {
                int b_l = wn * 32 + bg * 16 + col;
                bb[bg] = *(const s16x8*)(Al + b_l * 256 + ((gg ^ (b_l & 7)) << 3));
            }
            #pragma unroll
            for (int mf = 0; mf < 2; ++mf)
                #pragma unroll
                for (int bg = 0; bg < 2; ++bg)
                    acc[mf][bg] = __builtin_amdgcn_mfma_f32_16x16x32_bf16(
                        a[mf], bb[bg], acc[mf][bg], 0, 0, 0);
        }
        __syncthreads();
    }
    #pragma unroll
    for (int mf = 0; mf < 2; ++mf)
        #pragma unroll
        for (int bg = 0; bg < 2; ++bg)
            #pragma unroll
            for (int r = 0; r < 4; ++r) {
                int j = jt * 64 + wm * 32 + mf * 16 + quad * 4 + r;
                int b = wn * 32 + bg * 16 + col;
                partial[((size_t)ks * 512 + j) * 64 + b] = acc[mf][bg][r];
            }
}

__global__ __launch_bounds__(256) void fc1_reduce4(
    const float* __restrict__ partial, const float* __restrict__ bias,
    float* __restrict__ out)             // (64,512)
{
    int idx = blockIdx.x * 256 + threadIdx.x;
    int b = idx & 63, j = idx >> 6;
    float a = bias[j];
    #pragma unroll 8
    for (int ks = 0; ks < 64; ++ks)
        a += partial[((size_t)ks * 512 + j) * 64 + b];
    out[b * 512 + j] = fmaxf(a, 0.f);
}

__global__ __launch_bounds__(256) void fc2_kernel(
    const float* __restrict__ x,    // (64, 512)
    const float* __restrict__ w,    // (10, 512)
    const float* __restrict__ bias,
    float* __restrict__ out)        // (64, 10)
{
    int idx = blockIdx.x * 256 + threadIdx.x;
    if (idx >= 640) return;
    int n = idx % 10, b = idx / 10;
    float a = bias[n];
    const float* xr = x + b * 512;
    const float* wr = w + n * 512;
    for (int j = 0; j < 512; ++j) a = fmaf(xr[j], wr[j], a);
    out[idx] = a;
}

// ---------------------------------------------------------------------------
extern "C" void kernel_launch(void* const* d_in, const int* in_sizes, int n_in,
                              void* d_out, int out_size, void* d_ws, size_t ws_size,
                              hipStream_t stream) {
    const float* x   = (const float*)d_in[0];
    const float* c1w = (const float*)d_in[1];  const float* c1b = (const float*)d_in[2];
    const float* b1g = (const float*)d_in[3];  const float* b1b = (const float*)d_in[4];
    const float* b1m = (const float*)d_in[5];  const float* b1v = (const float*)d_in[6];
    const float* c2w = (const float*)d_in[7];  const float* c2b = (const float*)d_in[8];
    const float* b2g = (const float*)d_in[9];  const float* b2b = (const float*)d_in[10];
    const float* b2m = (const float*)d_in[11]; const float* b2v = (const float*)d_in[12];
    const float* c3w = (const float*)d_in[13]; const float* c3b = (const float*)d_in[14];
    const float* b3g = (const float*)d_in[15]; const float* b3b = (const float*)d_in[16];
    const float* b3m = (const float*)d_in[17]; const float* b3v = (const float*)d_in[18];
    const float* bw  = (const float*)d_in[19]; const float* bb  = (const float*)d_in[20];
    const float* cwh = (const float*)d_in[21]; const float* cww = (const float*)d_in[22];
    const float* f1w = (const float*)d_in[23]; const float* f1b = (const float*)d_in[24];
    const float* f2w = (const float*)d_in[25]; const float* f2b = (const float*)d_in[26];
    float* out = (float*)d_out;

    char* ws = (char*)d_ws;
    unsigned short* act1 = (unsigned short*)(ws + 0);           // [0,16M)
    unsigned short* act2 = (unsigned short*)(ws + 16777216);    // [16M,24M)
    unsigned short* act3 = (unsigned short*)(ws + 0);           // [0,3M)   (act1 dead)
    unsigned short* actB = (unsigned short*)(ws + 4194304);     // [4M,8M)
    float*          part = (float*)(ws + 8388608);              // [8M,16M) 64x512x64
    float*          fc1o = (float*)(ws + 0);                    // [0,128K) (act3 dead)
    unsigned short* wp2  = (unsigned short*)(ws + 25165824);    //  36,864 B
    unsigned short* wp3  = (unsigned short*)(ws + 25202688);    // 110,592 B
    unsigned short* wpL3 = (unsigned short*)(ws + 25313280);    // 884,736 B

    repack_w<<<2016, 256, 0, stream>>>(c2w, c3w, bw, wp2, wp3, wpL3);

    conv1_row<<<4096, 256, 0, stream>>>(x, c1w, c1b, b1g, b1b, b1m, b1v, act1);

    conv_mfma_pool<32, 64, 64, 4, 1, true, 1, 3, 1, 3>
        <<<2048, 256, 0, stream>>>(act1, wp2, c2b, b2g, b2b, b2m, b2v, act2);

    conv_mfma_pool<64, 96, 32, 2, 2, false, 0, 7, 0, 7>
        <<<1024, 256, 0, stream>>>(act2, wp3, c3b, b3g, b3b, b3m, b3v, act3);

    lrlc_mfma4<<<512, 512, 0, stream>>>(act3, wpL3, bb, cwh, cww, actB);

    fc1_lds<<<512, 256, 0, stream>>>(actB, f1w, part);
    fc1_reduce4<<<128, 256, 0, stream>>>(part, f1b, fc1o);
    fc2_kernel<<<3, 256, 0, stream>>>(fc1o, f2w, f2b, out);
}

// Round 10
// 126.839 us; speedup vs baseline: 23.6814x; 1.0737x over previous
//
#include <hip/hip_runtime.h>
#include <hip/hip_bf16.h>

#define EPS 1e-5f

typedef short s16x8 __attribute__((ext_vector_type(8)));
typedef float f32x4 __attribute__((ext_vector_type(4)));

__device__ __forceinline__ unsigned short f2bf(float f) {
    unsigned u = __float_as_uint(f);
    u += 0x7fffu + ((u >> 16) & 1u);
    return (unsigned short)(u >> 16);
}

// ---------------------------------------------------------------------------
// Repack conv weights. wp2/wp3: (CO, 9, CI) bf16. wpL3: LRLC weights in MFMA
// fragment order [s][cbk][g][rp][j][kk][lane][8e].
// ---------------------------------------------------------------------------
__global__ __launch_bounds__(256) void repack_w(
    const float* __restrict__ c2w, const float* __restrict__ c3w,
    const float* __restrict__ bw,
    unsigned short* __restrict__ wp2, unsigned short* __restrict__ wp3,
    unsigned short* __restrict__ wpL3)
{
    int idx = blockIdx.x * 256 + threadIdx.x;
    if (idx < 18432) {                       // conv2: 64 x 9 x 32
        int co = idx / 288, rem = idx % 288, s = rem / 32, ci = rem % 32;
        wp2[idx] = f2bf(c2w[(co * 32 + ci) * 9 + s]);
    } else if (idx < 73728) {                // conv3: 96 x 9 x 64
        int i = idx - 18432;
        int co = i / 576, rem = i % 576, s = rem / 64, ci = rem % 64;
        wp3[i] = f2bf(c3w[(co * 64 + ci) * 9 + s]);
    } else if (idx < 516096) {               // lrlc frag-order: 442368 elems
        int i = idx - 73728;
        int e    = i & 7;
        int lane = (i >> 3) & 63;
        int fk   = i >> 9;            // t*3 + kk
        int kk   = fk % 3;
        int t    = fk / 3;            // = (((s*4+cbk)*2+g)*2+rp)*2+j
        int j    = t & 1;
        int rp   = (t >> 1) & 1;
        int g    = (t >> 2) & 1;
        int cbk  = (t >> 3) & 3;
        int s    = t >> 5;
        int col = lane & 15, quad = lane >> 4;
        int cog = (rp * 2 + j) * 128 + cbk * 32 + g * 16 + col;
        int ci  = (kk * 4 + quad) * 8 + e;
        wpL3[i] = f2bf(bw[(cog * 96 + ci) * 9 + s]);
    }
}

// ---------------------------------------------------------------------------
// conv1 v3: block = (b, 4-ph group). Input strip staged ONCE in zero-padded
// LDS (no bounds checks, no redundant global loads); weights + folded BN in
// LDS; thread = (pw, ph_loc) holds 4x4 patch in regs (ds_read_b64,
// conflict-free) reused across ALL 32 channels; bf16 packed in VGPRs.
// ---------------------------------------------------------------------------
__global__ __launch_bounds__(256) void conv1_tile(
    const float* __restrict__ x,      // (64,1,128,128)
    const float* __restrict__ w,      // (32,1,3,3)
    const float* __restrict__ cbv, const float* __restrict__ gg,
    const float* __restrict__ bnb, const float* __restrict__ mm,
    const float* __restrict__ vv,
    unsigned short* __restrict__ out) // (64,64,64,32) NHWC bf16
{
    __shared__ float xs[10][132];     // rows ph4*8-1 .. +8, cols pad +1/+3
    __shared__ float wsm[288];
    __shared__ float sclsh[64];       // scl[32] | sh[32]

    const int tid = threadIdx.x;
    const int b = blockIdx.x >> 4, ph4 = blockIdx.x & 15;

    for (int i = tid; i < 10 * 132; i += 256) ((float*)xs)[i] = 0.f;
    for (int i = tid; i < 288; i += 256) wsm[i] = w[i];
    if (tid < 32) {
        float scl = gg[tid] * rsqrtf(vv[tid] + EPS);
        sclsh[tid]      = scl;
        sclsh[32 + tid] = (cbv[tid] - mm[tid]) * scl + bnb[tid];
    }
    __syncthreads();
    const int row0 = ph4 * 8 - 1;
    for (int i = tid; i < 10 * 128; i += 256) {
        int r = i >> 7, c = i & 127;
        int gr = row0 + r;
        if (gr >= 0 && gr < 128)
            xs[r][c + 1] = x[(size_t)b * 16384 + gr * 128 + c];
    }
    __syncthreads();

    const int pw = tid & 63, ph_loc = tid >> 6;
    // patch regs: xs rows 2*ph_loc .. +3, cols 2*pw .. +3 (8B-aligned pairs)
    float pr[4][4];
    #pragma unroll
    for (int rr = 0; rr < 4; ++rr) {
        float2 u0 = *(const float2*)&xs[2 * ph_loc + rr][2 * pw];
        float2 u1 = *(const float2*)&xs[2 * ph_loc + rr][2 * pw + 2];
        pr[rr][0] = u0.x; pr[rr][1] = u0.y; pr[rr][2] = u1.x; pr[rr][3] = u1.y;
    }

    unsigned ow[16];
    #pragma unroll 4
    for (int co = 0; co < 32; ++co) {
        float wv[9];
        #pragma unroll
        for (int i = 0; i < 9; ++i) wv[i] = wsm[co * 9 + i];
        float scl = sclsh[co], sh = sclsh[32 + co];
        float a00 = 0.f, a01 = 0.f, a10 = 0.f, a11 = 0.f;
        #pragma unroll
        for (int ky = 0; ky < 3; ++ky)
            #pragma unroll
            for (int kx = 0; kx < 3; ++kx) {
                float wk = wv[ky * 3 + kx];
                a00 = fmaf(wk, pr[ky][kx],         a00);
                a01 = fmaf(wk, pr[ky][kx + 1],     a01);
                a10 = fmaf(wk, pr[ky + 1][kx],     a10);
                a11 = fmaf(wk, pr[ky + 1][kx + 1], a11);
            }
        float y0 = fmaf(a00, scl, sh), y1 = fmaf(a01, scl, sh);
        float y2 = fmaf(a10, scl, sh), y3 = fmaf(a11, scl, sh);
        float o = fmaxf(fmaxf(fmaxf(y0, y1), fmaxf(y2, y3)), 0.f);
        unsigned u = (unsigned)f2bf(o);
        if ((co & 1) == 0) ow[co >> 1] = u;
        else               ow[co >> 1] |= u << 16;
    }

    const int PH = ph4 * 4 + ph_loc;
    unsigned short* dst = out + (((size_t)(b * 64 + PH)) * 64 + pw) * 32;
    #pragma unroll
    for (int q = 0; q < 4; ++q) {
        uint4 v = make_uint4(ow[q * 4], ow[q * 4 + 1], ow[q * 4 + 2], ow[q * 4 + 3]);
        *(uint4*)(dst + q * 8) = v;
    }
}

// ---------------------------------------------------------------------------
// Fused implicit-GEMM conv3x3 + BN + ReLU + pool2x2 via bf16 MFMA.
// blockIdx remapped XCD-aware: each XCD owns a contiguous hp-range per b.
// ---------------------------------------------------------------------------
template<int CI, int CO, int W, int NWM, int NWN, bool ALLB,
         int SASH, int SAMK, int SBSH, int SBMK>
__global__ __launch_bounds__(256) void conv_mfma_pool(
    const unsigned short* __restrict__ xin,
    const unsigned short* __restrict__ wpk,
    const float* __restrict__ cbv, const float* __restrict__ gg,
    const float* __restrict__ bnb, const float* __restrict__ mm,
    const float* __restrict__ vv,
    unsigned short* __restrict__ out)
{
    constexpr int WT  = W + 2;
    constexpr int NFW = CO / 16 / NWN;
    constexpr int CG  = CI / 8;
    constexpr int ASZ = 4 * WT * CI * 2;
    constexpr int BSZ = (ALLB ? 9 : 1) * CO * CI * 2;
    constexpr int KSTEPS = CI / 32;
    constexpr int PH2 = W / 2;
    constexpr int HPX = PH2 / 8;   // hp per XCD per b

    __shared__ __align__(16) unsigned char sm[ASZ + BSZ];

    const int tid = threadIdx.x;
    const int wave = tid >> 6, lane = tid & 63;
    const int quad = lane >> 4, col = lane & 15;
    const int wm = wave % NWM, wn = wave / NWM;

    const int xcd  = blockIdx.x & 7;
    const int slot = blockIdx.x >> 3;
    const int hp = xcd * HPX + (slot % HPX);
    const int b  = slot / HPX;

    constexpr int NCHA = 4 * WT * CG;
    for (int ch = tid; ch < NCHA; ch += 256) {
        int r    = ch / (WT * CG);
        int rem  = ch % (WT * CG);
        int wp   = rem / CG;
        int slot_ = rem % CG;
        int g = slot_ ^ ((wp >> SASH) & SAMK);
        int h = hp * 2 - 1 + r;
        int w = wp - 1;
        s16x8 val = {};
        if (h >= 0 && h < W && w >= 0 && w < W)
            val = *(const s16x8*)(xin + (((size_t)(b * W + h) * W + w) * CI + g * 8));
        *(s16x8*)(sm + ch * 16) = val;
    }
    if constexpr (ALLB) {
        constexpr int NCHB = CO * 9 * CG;
        for (int ch = tid; ch < NCHB; ch += 256) {
            int co   = ch / (9 * CG);
            int rem  = ch % (9 * CG);
            int s    = rem / CG;
            int slot_ = rem % CG;
            int g = slot_ ^ ((co >> SBSH) & SBMK);
            s16x8 val = *(const s16x8*)(wpk + ((co * 9 + s) * CI + g * 8));
            *(s16x8*)(sm + ASZ + ch * 16) = val;
        }
        __syncthreads();
    }

    f32x4 acc[2][NFW];
    #pragma unroll
    for (int i = 0; i < 2; ++i)
        #pragma unroll
        for (int j = 0; j < NFW; ++j) acc[i][j] = (f32x4){0.f, 0.f, 0.f, 0.f};

    #pragma unroll
    for (int s = 0; s < 9; ++s) {
        const int dy = s / 3, dx = s % 3;
        if constexpr (!ALLB) {
            __syncthreads();
            constexpr int NCHB = CO * CG;
            for (int ch = tid; ch < NCHB; ch += 256) {
                int co = ch / CG, slot_ = ch % CG;
                int g = slot_ ^ ((co >> SBSH) & SBMK);
                s16x8 val = *(const s16x8*)(wpk + ((co * 9 + s) * CI + g * 8));
                *(s16x8*)(sm + ASZ + ch * 16) = val;
            }
            __syncthreads();
        }
        #pragma unroll
        for (int kk = 0; kk < KSTEPS; ++kk) {
            const int g = kk * 4 + quad;
            s16x8 a[2];
            #pragma unroll
            for (int mi = 0; mi < 2; ++mi) {
                int wp = wm * 16 + col + dx;
                int r  = mi + dy;
                int addr = (r * WT + wp) * (CI * 2) + ((g ^ ((wp >> SASH) & SAMK)) << 4);
                a[mi] = *(const s16x8*)(sm + addr);
            }
            #pragma unroll
            for (int nf = 0; nf < NFW; ++nf) {
                int co_l = (wn * NFW + nf) * 16 + col;
                int row = ALLB ? (co_l * 9 + s) : co_l;
                int addr = ASZ + row * (CI * 2) + ((g ^ ((co_l >> SBSH) & SBMK)) << 4);
                s16x8 bf = *(const s16x8*)(sm + addr);
                acc[0][nf] = __builtin_amdgcn_mfma_f32_16x16x32_bf16(a[0], bf, acc[0][nf], 0, 0, 0);
                acc[1][nf] = __builtin_amdgcn_mfma_f32_16x16x32_bf16(a[1], bf, acc[1][nf], 0, 0, 0);
            }
        }
    }

    #pragma unroll
    for (int nf = 0; nf < NFW; ++nf) {
        int co = (wn * NFW + nf) * 16 + col;
        float scl = gg[co] * rsqrtf(vv[co] + EPS);
        float sh  = (cbv[co] - mm[co]) * scl + bnb[co];
        #pragma unroll
        for (int pr = 0; pr < 2; ++pr) {
            float y0 = fmaf(acc[0][nf][2 * pr],     scl, sh);
            float y1 = fmaf(acc[0][nf][2 * pr + 1], scl, sh);
            float y2 = fmaf(acc[1][nf][2 * pr],     scl, sh);
            float y3 = fmaf(acc[1][nf][2 * pr + 1], scl, sh);
            float o = fmaxf(fmaxf(fmaxf(y0, y1), fmaxf(y2, y3)), 0.f);
            int pw = wm * 8 + quad * 2 + pr;
            out[((size_t)(b * PH2 + hp) * PH2 + pw) * CO + co] = f2bf(o);
        }
    }
}

// ---------------------------------------------------------------------------
// LRLC v4: B loaded per-wave from fragment-ordered wpL3 (no B-LDS, 3 barriers
// total). A in LDS. 8 waves: (wm, g, rp).
// ---------------------------------------------------------------------------
__global__ __launch_bounds__(512) void lrlc_mfma4(
    const unsigned short* __restrict__ xin,  // (64,16,16,96) bf16
    const unsigned short* __restrict__ wpk3, // frag-ordered (442368)
    const float* __restrict__ bbias,         // (4,128)
    const float* __restrict__ cwh, const float* __restrict__ cww,
    unsigned short* __restrict__ actB)       // (64, 32768) bf16
{
    constexpr int CI = 96, WT = 18, NR = 10, CG = 12;
    constexpr int ASZ = NR * WT * CI * 2;    // 34560 B
    __shared__ __align__(16) unsigned char sm[ASZ];
    __shared__ float cwt[256][4];

    const int tid = threadIdx.x;
    const int wave = tid >> 6, lane = tid & 63;
    const int quad = lane >> 4, col = lane & 15;
    const int wm = wave & 1;
    const int g  = (wave >> 1) & 1;
    const int rp = wave >> 2;

    const int cbk = blockIdx.x & 3;
    const int mb  = (blockIdx.x >> 2) & 1;
    const int b   = blockIdx.x >> 3;

    if (tid < 256) {
        int h = tid >> 4, w = tid & 15;
        float e[4], mx = -1e30f;
        #pragma unroll
        for (int r = 0; r < 4; ++r) { e[r] = cwh[h * 4 + r] + cww[w * 4 + r]; mx = fmaxf(mx, e[r]); }
        float se = 0.f;
        #pragma unroll
        for (int r = 0; r < 4; ++r) { e[r] = expf(e[r] - mx); se += e[r]; }
        float inv = 1.f / se;
        #pragma unroll
        for (int r = 0; r < 4; ++r) cwt[tid][r] = e[r] * inv;
    }

    constexpr int NCHA = NR * WT * CG;  // 2160
    for (int ch = tid; ch < NCHA; ch += 512) {
        int r    = ch / (WT * CG);
        int rem  = ch % (WT * CG);
        int wp   = rem / CG, slot = rem % CG;
        int gg_ = slot ^ ((wp >> 1) & 3);
        int h = mb * 8 + r - 1;
        int w = wp - 1;
        s16x8 val = {};
        if (h >= 0 && h < 16 && w >= 0 && w < 16)
            val = *(const s16x8*)(xin + (((size_t)(b * 16 + h) * 16 + w) * CI + gg_ * 8));
        *(s16x8*)(sm + ch * 16) = val;
    }
    __syncthreads();

    f32x4 acc[4][2];
    #pragma unroll
    for (int i = 0; i < 4; ++i)
        #pragma unroll
        for (int j = 0; j < 2; ++j) acc[i][j] = (f32x4){0.f, 0.f, 0.f, 0.f};

    const int tbase = ((cbk * 2 + g) * 2 + rp);
    for (int s = 0; s < 9; ++s) {
        const int dy = s / 3, dx = s % 3;
        s16x8 bf[2][3];
        #pragma unroll
        for (int j = 0; j < 2; ++j)
            #pragma unroll
            for (int kk = 0; kk < 3; ++kk) {
                int fidx = ((s * 32 + tbase * 2 + j) * 3 + kk) * 512 + lane * 8;
                bf[j][kk] = *(const s16x8*)(wpk3 + fidx);
            }
        #pragma unroll
        for (int kk = 0; kk < 3; ++kk) {
            const int gg = kk * 4 + quad;
            s16x8 a[4];
            #pragma unroll
            for (int mi = 0; mi < 4; ++mi) {
                int mf = wm * 4 + mi;
                int r  = mf + dy;
                int wp = col + dx;
                int addr = (r * WT + wp) * (CI * 2) + ((gg ^ ((wp >> 1) & 3)) << 4);
                a[mi] = *(const s16x8*)(sm + addr);
            }
            #pragma unroll
            for (int mi = 0; mi < 4; ++mi)
                #pragma unroll
                for (int j = 0; j < 2; ++j)
                    acc[mi][j] = __builtin_amdgcn_mfma_f32_16x16x32_bf16(
                        a[mi], bf[j][kk], acc[mi][j], 0, 0, 0);
        }
    }
    __syncthreads();

    float* ldo = (float*)sm;   // [2][128][33]
    {
        const int c_lo = g * 16 + col;
        const int cg   = cbk * 32 + c_lo;
        float bbA = bbias[(rp * 2 + 0) * 128 + cg];
        float bbB = bbias[(rp * 2 + 1) * 128 + cg];
        #pragma unroll
        for (int mi = 0; mi < 4; ++mi) {
            int mf = wm * 4 + mi;
            #pragma unroll
            for (int rg = 0; rg < 4; ++rg) {
                int hwl = mf * 16 + quad * 4 + rg;
                int hwg = mb * 128 + hwl;
                float o = cwt[hwg][rp * 2]     * (acc[mi][0][rg] + bbA)
                        + cwt[hwg][rp * 2 + 1] * (acc[mi][1][rg] + bbB);
                ldo[(rp * 128 + hwl) * 33 + c_lo] = o;
            }
        }
    }
    __syncthreads();
    {
        int cl = tid >> 4;
        int sg = tid & 15;
        size_t base = (size_t)b * 32768 + (cbk * 32 + cl) * 256 + mb * 128 + sg * 8;
        s16x8 v;
        #pragma unroll
        for (int i = 0; i < 8; ++i) {
            int hw = sg * 8 + i;
            float o = ldo[hw * 33 + cl] + ldo[(128 + hw) * 33 + cl];
            v[i] = (short)f2bf(fmaxf(o, 0.f));
        }
        *(s16x8*)(actB + base) = v;
    }
}

// ---------------------------------------------------------------------------
// fc1 MFMA GEMM (R5-proven LDS operand path) + T14 register prefetch +
// XCD-aware ks mapping.
// ---------------------------------------------------------------------------
__global__ __launch_bounds__(256) void fc1_lds(
    const unsigned short* __restrict__ actB, // (64, 32768) bf16
    const float* __restrict__ w,             // (512, 32768) f32
    float* __restrict__ partial)             // (64, 512, 64)
{
    __shared__ __align__(16) unsigned short Wl[64 * 256];
    __shared__ __align__(16) unsigned short Al[64 * 256];

    const int tid = threadIdx.x;
    const int wave = tid >> 6, lane = tid & 63;
    const int quad = lane >> 4, col = lane & 15;
    const int wm = wave & 1, wn = wave >> 1;
    const int xcd  = blockIdx.x & 7;
    const int slot = blockIdx.x >> 3;
    const int ks = xcd * 8 + (slot >> 3);
    const int jt = slot & 7;

    const int rt  = tid >> 2;
    const int seg = tid & 3;

    const float* wsrc = w + (size_t)(jt * 64 + rt) * 32768 + ks * 512 + seg * 64;
    const unsigned short* asrc = actB + (size_t)rt * 32768 + ks * 512 + seg * 64;

    f32x4 acc[2][2];
    #pragma unroll
    for (int i = 0; i < 2; ++i)
        #pragma unroll
        for (int j = 0; j < 2; ++j) acc[i][j] = (f32x4){0.f, 0.f, 0.f, 0.f};

    float4 pw0[8], pw1[8]; s16x8 pa[8];
    #pragma unroll
    for (int u = 0; u < 8; ++u) {
        pw0[u] = *(const float4*)(wsrc + u * 8);
        pw1[u] = *(const float4*)(wsrc + u * 8 + 4);
        pa[u]  = *(const s16x8*)(asrc + u * 8);
    }

    #pragma unroll
    for (int c = 0; c < 2; ++c) {
        #pragma unroll
        for (int u = 0; u < 8; ++u) {
            s16x8 v;
            v[0] = (short)f2bf(pw0[u].x); v[1] = (short)f2bf(pw0[u].y);
            v[2] = (short)f2bf(pw0[u].z); v[3] = (short)f2bf(pw0[u].w);
            v[4] = (short)f2bf(pw1[u].x); v[5] = (short)f2bf(pw1[u].y);
            v[6] = (short)f2bf(pw1[u].z); v[7] = (short)f2bf(pw1[u].w);
            int phys = (seg * 8 + u) ^ (rt & 7);
            *(s16x8*)(Wl + rt * 256 + phys * 8) = v;
            *(s16x8*)(Al + rt * 256 + phys * 8) = pa[u];
        }
        __syncthreads();
        if (c == 0) {
            #pragma unroll
            for (int u = 0; u < 8; ++u) {
                pw0[u] = *(const float4*)(wsrc + 256 + u * 8);
                pw1[u] = *(const float4*)(wsrc + 256 + u * 8 + 4);
                pa[u]  = *(const s16x8*)(asrc + 256 + u * 8);
            }
        }
        #pragma unroll
        for (int kk = 0; kk < 8; ++kk) {
            const int gg = kk * 4 + quad;
            s16x8 a[2], bb[2];
            #pragma unroll
            for (int mf = 0; mf < 2; ++mf) {
                int j_l = wm * 32 + mf * 16 + col;
                a[mf] = *(const s16x8*)(Wl + j_l * 256 + ((gg ^ (j_l & 7)) << 3));
            }
            #pragma unroll
            for (int bg = 0; bg < 2; ++bg) {
                int b_l = wn * 32 + bg * 16 + col;
                bb[bg] = *(const s16x8*)(Al + b_l * 256 + ((gg ^ (b_l & 7)) << 3));
            }
            #pragma unroll
            for (int mf = 0; mf < 2; ++mf)
                #pragma unroll
                for (int bg = 0; bg < 2; ++bg)
                    acc[mf][bg] = __builtin_amdgcn_mfma_f32_16x16x32_bf16(
                        a[mf], bb[bg], acc[mf][bg], 0, 0, 0);
        }
        __syncthreads();
    }
    #pragma unroll
    for (int mf = 0; mf < 2; ++mf)
        #pragma unroll
        for (int bg = 0; bg < 2; ++bg)
            #pragma unroll
            for (int r = 0; r < 4; ++r) {
                int j = jt * 64 + wm * 32 + mf * 16 + quad * 4 + r;
                int b = wn * 32 + bg * 16 + col;
                partial[((size_t)ks * 512 + j) * 64 + b] = acc[mf][bg][r];
            }
}

__global__ __launch_bounds__(256) void fc1_reduce4(
    const float* __restrict__ partial, const float* __restrict__ bias,
    float* __restrict__ out)             // (64,512)
{
    int idx = blockIdx.x * 256 + threadIdx.x;
    int b = idx & 63, j = idx >> 6;
    float a = bias[j];
    #pragma unroll 8
    for (int ks = 0; ks < 64; ++ks)
        a += partial[((size_t)ks * 512 + j) * 64 + b];
    out[b * 512 + j] = fmaxf(a, 0.f);
}

__global__ __launch_bounds__(256) void fc2_kernel(
    const float* __restrict__ x,    // (64, 512)
    const float* __restrict__ w,    // (10, 512)
    const float* __restrict__ bias,
    float* __restrict__ out)        // (64, 10)
{
    int idx = blockIdx.x * 256 + threadIdx.x;
    if (idx >= 640) return;
    int n = idx % 10, b = idx / 10;
    float a = bias[n];
    const float* xr = x + b * 512;
    const float* wr = w + n * 512;
    for (int j = 0; j < 512; ++j) a = fmaf(xr[j], wr[j], a);
    out[idx] = a;
}

// ---------------------------------------------------------------------------
extern "C" void kernel_launch(void* const* d_in, const int* in_sizes, int n_in,
                              void* d_out, int out_size, void* d_ws, size_t ws_size,
                              hipStream_t stream) {
    const float* x   = (const float*)d_in[0];
    const float* c1w = (const float*)d_in[1];  const float* c1b = (const float*)d_in[2];
    const float* b1g = (const float*)d_in[3];  const float* b1b = (const float*)d_in[4];
    const float* b1m = (const float*)d_in[5];  const float* b1v = (const float*)d_in[6];
    const float* c2w = (const float*)d_in[7];  const float* c2b = (const float*)d_in[8];
    const float* b2g = (const float*)d_in[9];  const float* b2b = (const float*)d_in[10];
    const float* b2m = (const float*)d_in[11]; const float* b2v = (const float*)d_in[12];
    const float* c3w = (const float*)d_in[13]; const float* c3b = (const float*)d_in[14];
    const float* b3g = (const float*)d_in[15]; const float* b3b = (const float*)d_in[16];
    const float* b3m = (const float*)d_in[17]; const float* b3v = (const float*)d_in[18];
    const float* bw  = (const float*)d_in[19]; const float* bb  = (const float*)d_in[20];
    const float* cwh = (const float*)d_in[21]; const float* cww = (const float*)d_in[22];
    const float* f1w = (const float*)d_in[23]; const float* f1b = (const float*)d_in[24];
    const float* f2w = (const float*)d_in[25]; const float* f2b = (const float*)d_in[26];
    float* out = (float*)d_out;

    char* ws = (char*)d_ws;
    unsigned short* act1 = (unsigned short*)(ws + 0);           // [0,16M)
    unsigned short* act2 = (unsigned short*)(ws + 16777216);    // [16M,24M)
    unsigned short* act3 = (unsigned short*)(ws + 0);           // [0,3M)   (act1 dead)
    unsigned short* actB = (unsigned short*)(ws + 4194304);     // [4M,8M)
    float*          part = (float*)(ws + 8388608);              // [8M,16M) 64x512x64
    float*          fc1o = (float*)(ws + 0);                    // [0,128K) (act3 dead)
    unsigned short* wp2  = (unsigned short*)(ws + 25165824);    //  36,864 B
    unsigned short* wp3  = (unsigned short*)(ws + 25202688);    // 110,592 B
    unsigned short* wpL3 = (unsigned short*)(ws + 25313280);    // 884,736 B

    repack_w<<<2016, 256, 0, stream>>>(c2w, c3w, bw, wp2, wp3, wpL3);

    conv1_tile<<<1024, 256, 0, stream>>>(x, c1w, c1b, b1g, b1b, b1m, b1v, act1);

    conv_mfma_pool<32, 64, 64, 4, 1, true, 1, 3, 1, 3>
        <<<2048, 256, 0, stream>>>(act1, wp2, c2b, b2g, b2b, b2m, b2v, act2);

    conv_mfma_pool<64, 96, 32, 2, 2, false, 0, 7, 0, 7>
        <<<1024, 256, 0, stream>>>(act2, wp3, c3b, b3g, b3b, b3m, b3v, act3);

    lrlc_mfma4<<<512, 512, 0, stream>>>(act3, wpL3, bb, cwh, cww, actB);

    fc1_lds<<<512, 256, 0, stream>>>(actB, f1w, part);
    fc1_reduce4<<<128, 256, 0, stream>>>(part, f1b, fc1o);
    fc2_kernel<<<3, 256, 0, stream>>>(fc1o, f2w, f2b, out);
}